// Round 3
// baseline (303115.161 us; speedup 1.0000x reference)
//
#include <hip/hip_runtime.h>
#include <hip/hip_bf16.h>

// ---------------- constants ----------------
#define LL   12
#define DD   1024
#define FF   4096
#define TTOK 128
#define VV   50257
#define NBLK 256
#define NTH  512

// ---------------- small helpers ----------------
__device__ __host__ __forceinline__ unsigned short f2bf(float f) {
    union { float f; unsigned u; } x; x.f = f;
    unsigned r = x.u + 0x7fffu + ((x.u >> 16) & 1u);
    return (unsigned short)(r >> 16);
}

__device__ __forceinline__ void ld8(const float* p, float* o) {
    float4 a = ((const float4*)p)[0], b = ((const float4*)p)[1];
    o[0]=a.x; o[1]=a.y; o[2]=a.z; o[3]=a.w; o[4]=b.x; o[5]=b.y; o[6]=b.z; o[7]=b.w;
}

template<typename WT>
__device__ __forceinline__ void wload8(const WT* w, long off, float* o) {
    if constexpr (sizeof(WT) == 2) {
        uint4 u = *reinterpret_cast<const uint4*>((const unsigned short*)w + off);
        union { unsigned u; float f; } t;
        t.u = u.x << 16;         o[0] = t.f;
        t.u = u.x & 0xffff0000u; o[1] = t.f;
        t.u = u.y << 16;         o[2] = t.f;
        t.u = u.y & 0xffff0000u; o[3] = t.f;
        t.u = u.z << 16;         o[4] = t.f;
        t.u = u.z & 0xffff0000u; o[5] = t.f;
        t.u = u.w << 16;         o[6] = t.f;
        t.u = u.w & 0xffff0000u; o[7] = t.f;
    } else {
        ld8((const float*)w + off, o);
    }
}

__device__ __forceinline__ float dot8(const float* w, const float* x) {
    return w[0]*x[0]+w[1]*x[1]+w[2]*x[2]+w[3]*x[3]+w[4]*x[4]+w[5]*x[5]+w[6]*x[6]+w[7]*x[7];
}

// block stats over xl[1024] (512 threads): mean + rstd (E[x^2]-m^2 form)
__device__ __forceinline__ void bstats(const float* xl, float* red, float& m, float& rs) {
    int tid = threadIdx.x;
    float a = xl[tid], b = xl[tid + 512];
    float s0 = a + b, s1 = a*a + b*b;
    #pragma unroll
    for (int o = 32; o; o >>= 1) { s0 += __shfl_xor(s0, o, 64); s1 += __shfl_xor(s1, o, 64); }
    if ((tid & 63) == 0) { red[(tid >> 6) * 2] = s0; red[(tid >> 6) * 2 + 1] = s1; }
    __syncthreads();
    float ms = 0.f, qs = 0.f;
    #pragma unroll
    for (int w = 0; w < 8; ++w) { ms += red[w * 2]; qs += red[w * 2 + 1]; }
    ms *= (1.f / 1024.f); qs *= (1.f / 1024.f);
    m = ms; rs = rsqrtf(qs - ms * ms + 1e-5f);
    __syncthreads();
}

// ---------------- grid barrier (two-level, sense-reversing) ----------------
__device__ __forceinline__ void barrier_pre() {
    __builtin_amdgcn_fence(__ATOMIC_RELEASE, "agent");
    __syncthreads();
}

__device__ __forceinline__ void barrier_go(unsigned* bar, unsigned& lsense) {
    if (threadIdx.x == 0) {
        unsigned s = lsense ^ 1u;
        int g = blockIdx.x >> 5;
        unsigned prev = __hip_atomic_fetch_add(&bar[g * 16], 1u, __ATOMIC_RELAXED, __HIP_MEMORY_SCOPE_AGENT);
        bool done = false;
        if (prev == 31u) {
            unsigned p2 = __hip_atomic_fetch_add(&bar[128], 1u, __ATOMIC_RELAXED, __HIP_MEMORY_SCOPE_AGENT);
            if (p2 == 7u) {
                #pragma unroll
                for (int i = 0; i < 8; ++i)
                    __hip_atomic_store(&bar[i * 16], 0u, __ATOMIC_RELAXED, __HIP_MEMORY_SCOPE_AGENT);
                __hip_atomic_store(&bar[128], 0u, __ATOMIC_RELAXED, __HIP_MEMORY_SCOPE_AGENT);
                __hip_atomic_store(&bar[144], s, __ATOMIC_RELEASE, __HIP_MEMORY_SCOPE_AGENT);
                done = true;
            }
        }
        if (!done) {
            while (__hip_atomic_load(&bar[144], __ATOMIC_ACQUIRE, __HIP_MEMORY_SCOPE_AGENT) != s)
                __builtin_amdgcn_s_sleep(2);
        }
    }
    lsense ^= 1u;
    __syncthreads();
    __builtin_amdgcn_fence(__ATOMIC_ACQUIRE, "agent");
}

// ---------------- params ----------------
struct SP {
    const int* tok; const float* emb; const float* pos;
    const float *l0w, *l0b, *l1w, *l1b, *l2w, *l2b;
    const float *tmk, *tmv, *tmr, *tf, *tdr;
    const float *ftmk, *ftmr, *low, *lob;
    const void *kw, *vw, *rw, *ow, *fkw, *fvw, *frw;
    float *xg, *rwkv, *fr, *fk, *td;
    float *aa, *bb, *pp, *sxa, *sxf, *v1, *v2;
    float* XbT;          // [DD][TTOK] f32 (transposed lnout outputs)
    unsigned* bar;
};

// ---------------- persistent sequential kernel ----------------
template<typename WT>
__global__ __launch_bounds__(NTH) void spike_persist(SP P) {
    constexpr int LPRD = (sizeof(WT) == 2) ? 16 : 32;   // 128B lines per D-length row
    const WT* kw  = (const WT*)P.kw;
    const WT* vw  = (const WT*)P.vw;
    const WT* rw  = (const WT*)P.rw;
    const WT* ow  = (const WT*)P.ow;
    const WT* fkw = (const WT*)P.fkw;
    const WT* fvw = (const WT*)P.fvw;
    const WT* frw = (const WT*)P.frw;

    __shared__ float xl[DD], xas[DD], xfs[DD], xk[DD], xv[DD], xr[DD];
    __shared__ float red[16];
    __shared__ float part[8][3];

    const int tid  = threadIdx.x;
    const int b    = blockIdx.x;
    const int wid  = tid >> 6;
    const int lane = tid & 63;
    const int h    = wid & 1;                // half of the wave pair
    const int c    = (b << 2) + (wid >> 1);  // channel owned by this wave pair
    const int c0   = b << 2;

    unsigned lsense = 0;
    float pfacc = 0.f;

    // ---- init states (covers LL*DD with blocks 0..23) ----
    for (int i = b * NTH + tid; i < LL * DD; i += NBLK * NTH) {
        P.aa[i] = 0.f; P.bb[i] = 0.f; P.pp[i] = -1e30f;
        P.sxa[i] = 0.f; P.sxf[i] = 0.f; P.v1[i] = 0.f; P.v2[i] = 0.f;
        P.td[i] = -expf(P.tdr[i]);
    }
    barrier_pre();
    barrier_go(P.bar, lsense);

    #pragma unroll 1
    for (int t = 0; t <= TTOK; ++t) {
        // ---- prologue: emit lnout(x) of previous token (transposed, f32) ----
        if (t > 0) {
            xl[tid] = P.xg[tid]; xl[tid + 512] = P.xg[tid + 512];
            __syncthreads();
            float m, rs; bstats(xl, red, m, rs);
            if (tid < 4) {
                int cc = c0 + tid;
                P.XbT[(size_t)cc * TTOK + (t - 1)] =
                    (xl[cc] - m) * rs * P.low[cc] + P.lob[cc];
            }
            __syncthreads();
        }
        if (t == TTOK) break;

        // ---- token embedding + ln0 (redundant per block) ----
        {
            int tk0 = P.tok[t];
            float e0 = P.emb[(size_t)tk0 * DD + tid]       + P.pos[(size_t)t * DD + tid];
            float e1 = P.emb[(size_t)tk0 * DD + tid + 512] + P.pos[(size_t)t * DD + tid + 512];
            xl[tid] = e0; xl[tid + 512] = e1;
            __syncthreads();
            float m, rs; bstats(xl, red, m, rs);
            xl[tid]       = (e0 - m) * rs * P.l0w[tid]       + P.l0b[tid];
            xl[tid + 512] = (e1 - m) * rs * P.l0w[tid + 512] + P.l0b[tid + 512];
            __syncthreads();
        }

        #pragma unroll 1
        for (int l = 0; l < LL; ++l) {
            const int ld = l * DD;
            // ========== stage A: LN1, mixes, r/k/v dots, WKV ==========
            if (l > 0) {
                xl[tid] = P.xg[tid]; xl[tid + 512] = P.xg[tid + 512];
                __syncthreads();
            }
            float m1, rs1; bstats(xl, red, m1, rs1);
            for (int i = tid; i < DD; i += NTH) {
                float a = (xl[i] - m1) * rs1 * P.l1w[ld + i] + P.l1b[ld + i];
                xas[i] = a;
                float sx = P.sxa[ld + i];
                float u;
                u = P.tmk[ld + i]; xk[i] = a * u + sx * (1.f - u);
                u = P.tmv[ld + i]; xv[i] = a * u + sx * (1.f - u);
                u = P.tmr[ld + i]; xr[i] = a * u + sx * (1.f - u);
            }
            __syncthreads();
            {
                int base = h * 512 + lane * 8;
                long roff = ((long)ld + c) * DD + base;
                float wf[8], x8[8], sk, sv, sr;
                wload8<WT>(kw, roff, wf); ld8(&xk[base], x8); sk = dot8(wf, x8);
                wload8<WT>(vw, roff, wf); ld8(&xv[base], x8); sv = dot8(wf, x8);
                wload8<WT>(rw, roff, wf); ld8(&xr[base], x8); sr = dot8(wf, x8);
                #pragma unroll
                for (int o = 32; o; o >>= 1) {
                    sk += __shfl_xor(sk, o, 64); sv += __shfl_xor(sv, o, 64); sr += __shfl_xor(sr, o, 64);
                }
                if (lane == 0) { part[wid][0] = sk; part[wid][1] = sv; part[wid][2] = sr; }
            }
            __syncthreads();
            if ((tid & 127) == 0) {
                float kk = part[wid][0] + part[wid + 1][0];
                float vv = part[wid][1] + part[wid + 1][1];
                float rr = part[wid][2] + part[wid + 1][2];
                int si = ld + c;
                float aa = P.aa[si], bb = P.bb[si], pp = P.pp[si];
                float ww = P.tf[si] + kk;
                float q  = fmaxf(pp, ww);
                float e1 = expf(pp - q), e2 = expf(ww - q);
                float an = e1 * aa + e2 * vv, bn = e1 * bb + e2;
                float ww2 = pp + P.td[si];
                float q2  = fmaxf(ww2, kk);
                float e1b = expf(ww2 - q2), e2b = expf(kk - q2);
                P.aa[si] = e1b * aa + e2b * vv;
                P.bb[si] = e1b * bb + e2b;
                P.pp[si] = q2;
                float sg = 1.f / (1.f + expf(-rr));
                P.rwkv[c] = sg * (an / bn);
            }
            barrier_pre();
            float pfv = 0.f;
            if (tid < 4 * LPRD) {  // prefetch ow rows into L2
                int rr2 = c0 + tid / LPRD, li = tid % LPRD;
                pfv = ((const float*)(ow + ((long)ld + rr2) * DD))[li * 32];
            }
            barrier_go(P.bar, lsense);
            pfacc += pfv;

            // ========== stage B: o = ow@rwkv, LIF(v1), x += s ==========
            if (tid < 4) P.sxa[ld + c0 + tid] = xas[c0 + tid];
            {
                int base = h * 512 + lane * 8;
                long roff = ((long)ld + c) * DD + base;
                float wf[8], g8[8];
                wload8<WT>(ow, roff, wf);
                ld8(&P.rwkv[base], g8);
                float so = dot8(wf, g8);
                #pragma unroll
                for (int o = 32; o; o >>= 1) so += __shfl_xor(so, o, 64);
                if (lane == 0) part[wid][0] = so;
            }
            __syncthreads();
            if ((tid & 127) == 0) {
                float o_ = part[wid][0] + part[wid + 1][0];
                int si = ld + c;
                float v1o = P.v1[si];
                float vn = v1o + (o_ - v1o) * 0.5f;
                float s = (vn >= 1.f) ? 1.f : 0.f;
                P.v1[si] = vn * (1.f - s);
                P.xg[c] = xl[c] + s;
            }
            barrier_pre();
            pfv = 0.f;
            {   // prefetch fkw (16 rows) + frw (4 rows)
                int tot1 = 16 * LPRD;
                for (int q = tid; q < tot1 + 4 * LPRD; q += NTH) {
                    const float* ad;
                    if (q < tot1) {
                        int j = q / LPRD, li = q % LPRD;
                        int row = (b << 3) + (j & 7) + ((j >> 3) << 11);
                        ad = (const float*)(fkw + ((long)l * FF + row) * DD) + li * 32;
                    } else {
                        int q2 = q - tot1; int rr2 = c0 + q2 / LPRD, li = q2 % LPRD;
                        ad = (const float*)(frw + ((long)ld + rr2) * DD) + li * 32;
                    }
                    pfv += *ad;
                }
            }
            barrier_go(P.bar, lsense);
            pfacc += pfv;

            // ========== stage C: LN2, mixes, fk/fr dots ==========
            xl[tid] = P.xg[tid]; xl[tid + 512] = P.xg[tid + 512];
            __syncthreads();
            float m2, rs2; bstats(xl, red, m2, rs2);
            for (int i = tid; i < DD; i += NTH) {
                float f = (xl[i] - m2) * rs2 * P.l2w[ld + i] + P.l2b[ld + i];
                xfs[i] = f;
                float sx = P.sxf[ld + i];
                float u;
                u = P.ftmk[ld + i]; xk[i] = f * u + sx * (1.f - u);
                u = P.ftmr[ld + i]; xr[i] = f * u + sx * (1.f - u);
            }
            __syncthreads();
            #pragma unroll
            for (int rep = 0; rep < 2; ++rep) {
                int row = (b << 3) + wid + (rep << 11);
                long roff = ((long)l * FF + row) * DD + lane * 16;
                float wf[8], x8[8];
                wload8<WT>(fkw, roff, wf);     ld8(&xk[lane * 16], x8);     float s = dot8(wf, x8);
                wload8<WT>(fkw, roff + 8, wf); ld8(&xk[lane * 16 + 8], x8); s += dot8(wf, x8);
                #pragma unroll
                for (int o = 32; o; o >>= 1) s += __shfl_xor(s, o, 64);
                if (lane == 0) { float r_ = fmaxf(s, 0.f); P.fk[row] = r_ * r_; }
            }
            {
                int base = h * 512 + lane * 8;
                long roff = ((long)ld + c) * DD + base;
                float wf[8], x8[8];
                wload8<WT>(frw, roff, wf); ld8(&xr[base], x8);
                float s = dot8(wf, x8);
                #pragma unroll
                for (int o = 32; o; o >>= 1) s += __shfl_xor(s, o, 64);
                if (lane == 0) part[wid][0] = s;
            }
            __syncthreads();
            if ((tid & 127) == 0) {
                float s = part[wid][0] + part[wid + 1][0];
                P.fr[c] = 1.f / (1.f + expf(-s));
            }
            barrier_pre();
            pfv = 0.f;
            {   // prefetch fvw rows (F-length)
                int LPRF = LPRD * 4;
                for (int q = tid; q < 4 * LPRF; q += NTH) {
                    int rr2 = c0 + q / LPRF, li = q % LPRF;
                    pfv += ((const float*)(fvw + ((long)ld + rr2) * FF))[li * 32];
                }
            }
            barrier_go(P.bar, lsense);
            pfacc += pfv;

            // ========== stage D: fv = fvw@fk, LIF(v2), x += s, rescale ==========
            if (tid < 4) P.sxf[ld + c0 + tid] = xfs[c0 + tid];
            {
                long roff = ((long)ld + c) * FF + (h << 11) + lane * 32;
                const float* fkp = &P.fk[(h << 11) + lane * 32];
                float s = 0.f;
                #pragma unroll
                for (int u2 = 0; u2 < 4; ++u2) {
                    float wf[8], g8[8];
                    wload8<WT>(fvw, roff + u2 * 8, wf);
                    ld8(fkp + u2 * 8, g8);
                    s += dot8(wf, g8);
                }
                #pragma unroll
                for (int o = 32; o; o >>= 1) s += __shfl_xor(s, o, 64);
                if (lane == 0) part[wid][0] = s;
            }
            __syncthreads();
            if ((tid & 127) == 0) {
                float fv = part[wid][0] + part[wid + 1][0];
                float hh = P.fr[c] * fv;
                int si = ld + c;
                float v2o = P.v2[si];
                float vn = v2o + (hh - v2o) * 0.5f;
                float s = (vn >= 1.f) ? 1.f : 0.f;
                P.v2[si] = vn * (1.f - s);
                float xn = xl[c] + s;
                if (((l + 1) % 6) == 0) xn *= 0.5f;
                P.xg[c] = xn;
            }
            barrier_pre();
            pfv = 0.f;
            {   // prefetch next layer's kw/vw/rw rows
                int lnx = (l + 1) % LL;
                for (int q = tid; q < 12 * LPRD; q += NTH) {
                    int mm = q / (4 * LPRD), q2 = q % (4 * LPRD);
                    int rr2 = c0 + q2 / LPRD, li = q2 % LPRD;
                    const WT* mp = (mm == 0) ? kw : ((mm == 1) ? vw : rw);
                    pfv += ((const float*)(mp + ((long)lnx * DD + rr2) * DD))[li * 32];
                }
            }
            barrier_go(P.bar, lsense);
            pfacc += pfv;
        }
    }
    if (tid == 0 && pfacc == 1.2345e37f) P.xg[0] = 0.f;  // keep prefetch loads alive
}

// ---------------- VALU head: out[t][v] = sum_k head[v][k]*XbT[k][t]  (f32 out!) ----------------
__global__ __launch_bounds__(256) void head_simple(const float* __restrict__ head,
                                                   const float* __restrict__ XbT,
                                                   float* __restrict__ out) {
    int wv   = __builtin_amdgcn_readfirstlane(threadIdx.x >> 6);
    int lane = threadIdx.x & 63;
    int v0   = (blockIdx.x * 4 + wv) * 8;
    if (v0 >= VV) return;                      // wave-uniform
    const float* hp[8];
    #pragma unroll
    for (int r = 0; r < 8; ++r) {
        int v = v0 + r; if (v >= VV) v = VV - 1;   // clamp (stores guarded below)
        hp[r] = head + (size_t)v * DD;
    }
    float a0[8], a1[8];
    #pragma unroll
    for (int r = 0; r < 8; ++r) { a0[r] = 0.f; a1[r] = 0.f; }
    #pragma unroll 4
    for (int k = 0; k < DD; ++k) {
        float2 x2 = *(const float2*)(XbT + (size_t)k * TTOK + lane * 2);
        #pragma unroll
        for (int r = 0; r < 8; ++r) {
            float hv = hp[r][k];
            a0[r] += hv * x2.x;
            a1[r] += hv * x2.y;
        }
    }
    int t0 = lane * 2, t1 = t0 + 1;
    #pragma unroll
    for (int r = 0; r < 8; ++r) {
        int v = v0 + r;
        if (v < VV) {
            out[(size_t)t0 * VV + v] = a0[r];
            out[(size_t)t1 * VV + v] = a1[r];
        }
    }
}

// ---------------- fp32 -> bf16 conversion ----------------
__global__ void cvt_bf16(const float* __restrict__ s, unsigned short* __restrict__ d, long n) {
    long i = ((long)blockIdx.x * blockDim.x + threadIdx.x) * 4;
    long st = (long)gridDim.x * blockDim.x * 4;
    for (; i < n; i += st) {
        float4 f = *(const float4*)(s + i);
        ushort4 o;
        o.x = f2bf(f.x); o.y = f2bf(f.y); o.z = f2bf(f.z); o.w = f2bf(f.w);
        *(ushort4*)(d + i) = o;
    }
}

// ---------------- host launch ----------------
extern "C" void kernel_launch(void* const* d_in, const int* in_sizes, int n_in,
                              void* d_out, int out_size, void* d_ws, size_t ws_size,
                              hipStream_t stream) {
    (void)in_sizes; (void)n_in; (void)out_size;
    char* base = (char*)d_ws;
    size_t off = 0;
    auto take = [&](size_t bytes) -> void* {
        void* p = base + off;
        off = (off + bytes + 255) & ~(size_t)255;
        return p;
    };
    unsigned* bar = (unsigned*)take(1024);
    float* xg   = (float*)take(DD * 4);
    float* rwkv = (float*)take(DD * 4);
    float* fr   = (float*)take(DD * 4);
    float* fk   = (float*)take(FF * 4);
    float* td   = (float*)take(LL * DD * 4);
    float* aa   = (float*)take(LL * DD * 4);
    float* bb   = (float*)take(LL * DD * 4);
    float* pp   = (float*)take(LL * DD * 4);
    float* sxa  = (float*)take(LL * DD * 4);
    float* sxf  = (float*)take(LL * DD * 4);
    float* v1   = (float*)take(LL * DD * 4);
    float* v2   = (float*)take(LL * DD * 4);
    float* XbT  = (float*)take((size_t)DD * TTOK * 4);
    size_t wDD = (size_t)LL * DD * DD;
    size_t wFD = (size_t)LL * FF * DD;
    unsigned short* kwb  = (unsigned short*)take(wDD * 2);
    unsigned short* vwb  = (unsigned short*)take(wDD * 2);
    unsigned short* rwb  = (unsigned short*)take(wDD * 2);
    unsigned short* owb  = (unsigned short*)take(wDD * 2);
    unsigned short* frwb = (unsigned short*)take(wDD * 2);
    unsigned short* fkwb = (unsigned short*)take(wFD * 2);
    unsigned short* fvwb = (unsigned short*)take(wFD * 2);
    bool usebf = (ws_size >= off);

    hipMemsetAsync(bar, 0, 1024, stream);

    SP P;
    P.tok = (const int*)d_in[0];
    P.emb = (const float*)d_in[1];
    P.pos = (const float*)d_in[2];
    P.l0w = (const float*)d_in[3];  P.l0b = (const float*)d_in[4];
    P.l1w = (const float*)d_in[5];  P.l1b = (const float*)d_in[6];
    P.l2w = (const float*)d_in[7];  P.l2b = (const float*)d_in[8];
    P.tmk = (const float*)d_in[9];  P.tmv = (const float*)d_in[10]; P.tmr = (const float*)d_in[11];
    P.tf  = (const float*)d_in[12]; P.tdr = (const float*)d_in[13];
    P.ftmk = (const float*)d_in[18]; P.ftmr = (const float*)d_in[19];
    P.low = (const float*)d_in[23]; P.lob = (const float*)d_in[24];
    P.xg = xg; P.rwkv = rwkv; P.fr = fr; P.fk = fk; P.td = td;
    P.aa = aa; P.bb = bb; P.pp = pp; P.sxa = sxa; P.sxf = sxf; P.v1 = v1; P.v2 = v2;
    P.XbT = XbT; P.bar = bar;

    if (usebf) {
        struct CV { const float* s; unsigned short* d; size_t n; } cv[7] = {
            {(const float*)d_in[14], kwb,  wDD}, {(const float*)d_in[15], vwb,  wDD},
            {(const float*)d_in[16], rwb,  wDD}, {(const float*)d_in[17], owb,  wDD},
            {(const float*)d_in[22], frwb, wDD},
            {(const float*)d_in[20], fkwb, wFD}, {(const float*)d_in[21], fvwb, wFD},
        };
        for (int i = 0; i < 7; ++i)
            cvt_bf16<<<dim3(2048), dim3(256), 0, stream>>>(cv[i].s, cv[i].d, (long)cv[i].n);
        P.kw = kwb; P.vw = vwb; P.rw = rwb; P.ow = owb; P.fkw = fkwb; P.fvw = fvwb; P.frw = frwb;
        spike_persist<unsigned short><<<dim3(NBLK), dim3(NTH), 0, stream>>>(P);
    } else {
        P.kw = d_in[14]; P.vw = d_in[15]; P.rw = d_in[16]; P.ow = d_in[17];
        P.fkw = d_in[20]; P.fvw = d_in[21]; P.frw = d_in[22];
        spike_persist<float><<<dim3(NBLK), dim3(NTH), 0, stream>>>(P);
    }
    // head: 8 v-rows per wave, 4 waves per block
    int nwave = (VV + 7) / 8;
    int nblk  = (nwave + 3) / 4;
    head_simple<<<dim3(nblk), dim3(256), 0, stream>>>((const float*)d_in[25], XbT,
                                                      (float*)d_out);
}

// Round 4
// 40210.730 us; speedup vs baseline: 7.5382x; 7.5382x over previous
//
#include <hip/hip_runtime.h>
#include <hip/hip_bf16.h>

// ---------------- constants ----------------
#define LL   12
#define DD   1024
#define FF   4096
#define TTOK 128
#define VV   50257
#define NBLK 256
#define NTH  512

// ---------------- coherent (cross-XCD) access helpers ----------------
// Relaxed agent-scope atomics lower to sc1 loads/stores: they read/write the
// coherence point (shared L3) WITHOUT L2 invalidate/writeback instructions.
__device__ __forceinline__ float cld(const float* p) {
    return __hip_atomic_load((float*)p, __ATOMIC_RELAXED, __HIP_MEMORY_SCOPE_AGENT);
}
__device__ __forceinline__ void cst(float* p, float v) {
    __hip_atomic_store(p, v, __ATOMIC_RELAXED, __HIP_MEMORY_SCOPE_AGENT);
}

// ---------------- small helpers ----------------
__device__ __host__ __forceinline__ unsigned short f2bf(float f) {
    union { float f; unsigned u; } x; x.f = f;
    unsigned r = x.u + 0x7fffu + ((x.u >> 16) & 1u);
    return (unsigned short)(r >> 16);
}

__device__ __forceinline__ void ld8(const float* p, float* o) {
    float4 a = ((const float4*)p)[0], b = ((const float4*)p)[1];
    o[0]=a.x; o[1]=a.y; o[2]=a.z; o[3]=a.w; o[4]=b.x; o[5]=b.y; o[6]=b.z; o[7]=b.w;
}

template<typename WT>
__device__ __forceinline__ void wload8(const WT* w, long off, float* o) {
    if constexpr (sizeof(WT) == 2) {
        uint4 u = *reinterpret_cast<const uint4*>((const unsigned short*)w + off);
        union { unsigned u; float f; } t;
        t.u = u.x << 16;         o[0] = t.f;
        t.u = u.x & 0xffff0000u; o[1] = t.f;
        t.u = u.y << 16;         o[2] = t.f;
        t.u = u.y & 0xffff0000u; o[3] = t.f;
        t.u = u.z << 16;         o[4] = t.f;
        t.u = u.z & 0xffff0000u; o[5] = t.f;
        t.u = u.w << 16;         o[6] = t.f;
        t.u = u.w & 0xffff0000u; o[7] = t.f;
    } else {
        ld8((const float*)w + off, o);
    }
}

__device__ __forceinline__ float dot8(const float* w, const float* x) {
    return w[0]*x[0]+w[1]*x[1]+w[2]*x[2]+w[3]*x[3]+w[4]*x[4]+w[5]*x[5]+w[6]*x[6]+w[7]*x[7];
}

// block stats over xl[1024] (512 threads): mean + rstd
__device__ __forceinline__ void bstats(const float* xl, float* red, float& m, float& rs) {
    int tid = threadIdx.x;
    float a = xl[tid], b = xl[tid + 512];
    float s0 = a + b, s1 = a*a + b*b;
    #pragma unroll
    for (int o = 32; o; o >>= 1) { s0 += __shfl_xor(s0, o, 64); s1 += __shfl_xor(s1, o, 64); }
    if ((tid & 63) == 0) { red[(tid >> 6) * 2] = s0; red[(tid >> 6) * 2 + 1] = s1; }
    __syncthreads();
    float ms = 0.f, qs = 0.f;
    #pragma unroll
    for (int w = 0; w < 8; ++w) { ms += red[w * 2]; qs += red[w * 2 + 1]; }
    ms *= (1.f / 1024.f); qs *= (1.f / 1024.f);
    m = ms; rs = rsqrtf(qs - ms * ms + 1e-5f);
    __syncthreads();
}

// ---------------- grid barrier: fence-free, two-level, sense-reversing -------
// bar layout (uints): bar[g*16] g<8 group counters; bar[128] root;
//                     bar[160 + g*16] per-group sense copies.
// __syncthreads() before arrival drains each wave's sc1 stores (vmcnt(0)) so
// data is at L3 before the arrival increment. No wbl2/inv anywhere.
__device__ __forceinline__ void gbar_arrive(unsigned* bar, unsigned lsense) {
    __syncthreads();
    if (threadIdx.x == 0) {
        unsigned s = lsense ^ 1u;
        int g = blockIdx.x >> 5;
        unsigned prev = __hip_atomic_fetch_add(&bar[g * 16], 1u,
                            __ATOMIC_RELAXED, __HIP_MEMORY_SCOPE_AGENT);
        if (prev == 31u) {
            unsigned p2 = __hip_atomic_fetch_add(&bar[128], 1u,
                              __ATOMIC_RELAXED, __HIP_MEMORY_SCOPE_AGENT);
            if (p2 == 7u) {
                #pragma unroll
                for (int i = 0; i < 8; ++i)
                    __hip_atomic_store(&bar[i * 16], 0u, __ATOMIC_RELAXED, __HIP_MEMORY_SCOPE_AGENT);
                __hip_atomic_store(&bar[128], 0u, __ATOMIC_RELAXED, __HIP_MEMORY_SCOPE_AGENT);
                asm volatile("s_waitcnt vmcnt(0)" ::: "memory"); // resets land before sense flips
                #pragma unroll
                for (int i = 0; i < 8; ++i)
                    __hip_atomic_store(&bar[160 + i * 16], s, __ATOMIC_RELAXED, __HIP_MEMORY_SCOPE_AGENT);
            }
        }
    }
}

__device__ __forceinline__ void gbar_wait(unsigned* bar, unsigned& lsense) {
    unsigned s = lsense ^ 1u;
    if (threadIdx.x == 0) {
        int g = blockIdx.x >> 5;
        while (__hip_atomic_load(&bar[160 + g * 16], __ATOMIC_RELAXED,
                                 __HIP_MEMORY_SCOPE_AGENT) != s)
            __builtin_amdgcn_s_sleep(4);
    }
    lsense = s;
    __syncthreads();
}

// ---------------- params ----------------
struct SP {
    const int* tok; const float* emb; const float* pos;
    const float *l0w, *l0b, *l1w, *l1b, *l2w, *l2b;
    const float *tmk, *tmv, *tmr, *tf, *tdr;
    const float *ftmk, *ftmr, *low, *lob;
    const void *kw, *vw, *rw, *ow, *fkw, *fvw, *frw;
    float *xg, *rwkv, *fk, *td;
    float *aa, *bb, *pp, *sxa, *sxf, *v1, *v2;
    float* XbT;          // [DD][TTOK] f32 (transposed lnout outputs)
    unsigned* bar;
};

// ---------------- persistent sequential kernel ----------------
template<typename WT>
__global__ __launch_bounds__(NTH) void spike_persist(SP P) {
    constexpr int LPRD = (sizeof(WT) == 2) ? 16 : 32;   // 128B lines per D-length row
    const WT* kw  = (const WT*)P.kw;
    const WT* vw  = (const WT*)P.vw;
    const WT* rw  = (const WT*)P.rw;
    const WT* ow  = (const WT*)P.ow;
    const WT* fkw = (const WT*)P.fkw;
    const WT* fvw = (const WT*)P.fvw;
    const WT* frw = (const WT*)P.frw;

    __shared__ float xl[DD], xas[DD], xfs[DD], xk[DD], xv[DD], xr[DD];
    __shared__ float fkl[FF];
    __shared__ float red[16];
    __shared__ float part[8][3];
    __shared__ float frl[4];

    const int tid  = threadIdx.x;
    const int b    = blockIdx.x;
    const int wid  = tid >> 6;
    const int lane = tid & 63;
    const int h    = wid & 1;                // half of the wave pair
    const int c    = (b << 2) + (wid >> 1);  // channel owned by this wave pair
    const int c0   = b << 2;

    unsigned lsense = 0;
    float pfacc = 0.f;

    // ---- init states (write-through: read cross-XCD later) ----
    for (int i = b * NTH + tid; i < LL * DD; i += NBLK * NTH) {
        cst(&P.aa[i], 0.f); cst(&P.bb[i], 0.f); cst(&P.pp[i], -1e30f);
        cst(&P.sxa[i], 0.f); cst(&P.sxf[i], 0.f);
        cst(&P.v1[i], 0.f); cst(&P.v2[i], 0.f);
        cst(&P.td[i], -expf(P.tdr[i]));
    }
    gbar_arrive(P.bar, lsense);
    gbar_wait(P.bar, lsense);

    #pragma unroll 1
    for (int t = 0; t <= TTOK; ++t) {
        // ---- prologue: emit lnout(x) of previous token (transposed, f32) ----
        if (t > 0) {
            xl[tid] = cld(&P.xg[tid]); xl[tid + 512] = cld(&P.xg[tid + 512]);
            __syncthreads();
            float m, rs; bstats(xl, red, m, rs);
            if (tid < 4) {
                int cc = c0 + tid;
                P.XbT[(size_t)cc * TTOK + (t - 1)] =
                    (xl[cc] - m) * rs * P.low[cc] + P.lob[cc];
            }
            __syncthreads();
        }
        if (t == TTOK) break;

        // ---- token embedding + ln0 (redundant per block) ----
        {
            int tk0 = P.tok[t];
            float e0 = P.emb[(size_t)tk0 * DD + tid]       + P.pos[(size_t)t * DD + tid];
            float e1 = P.emb[(size_t)tk0 * DD + tid + 512] + P.pos[(size_t)t * DD + tid + 512];
            xl[tid] = e0; xl[tid + 512] = e1;
            __syncthreads();
            float m, rs; bstats(xl, red, m, rs);
            xl[tid]       = (e0 - m) * rs * P.l0w[tid]       + P.l0b[tid];
            xl[tid + 512] = (e1 - m) * rs * P.l0w[tid + 512] + P.l0b[tid + 512];
            __syncthreads();
        }

        #pragma unroll 1
        for (int l = 0; l < LL; ++l) {
            const int ld = l * DD;
            // ========== stage A: LN1, mixes, r/k/v dots, WKV ==========
            if (l > 0) {
                xl[tid] = cld(&P.xg[tid]); xl[tid + 512] = cld(&P.xg[tid + 512]);
                __syncthreads();
            }
            float m1, rs1; bstats(xl, red, m1, rs1);
            for (int i = tid; i < DD; i += NTH) {
                float a = (xl[i] - m1) * rs1 * P.l1w[ld + i] + P.l1b[ld + i];
                xas[i] = a;
                float sx = cld(&P.sxa[ld + i]);
                float u;
                u = P.tmk[ld + i]; xk[i] = a * u + sx * (1.f - u);
                u = P.tmv[ld + i]; xv[i] = a * u + sx * (1.f - u);
                u = P.tmr[ld + i]; xr[i] = a * u + sx * (1.f - u);
            }
            __syncthreads();
            {
                int base = h * 512 + lane * 8;
                long roff = ((long)ld + c) * DD + base;
                float wf[8], x8[8], sk, sv, sr;
                wload8<WT>(kw, roff, wf); ld8(&xk[base], x8); sk = dot8(wf, x8);
                wload8<WT>(vw, roff, wf); ld8(&xv[base], x8); sv = dot8(wf, x8);
                wload8<WT>(rw, roff, wf); ld8(&xr[base], x8); sr = dot8(wf, x8);
                #pragma unroll
                for (int o = 32; o; o >>= 1) {
                    sk += __shfl_xor(sk, o, 64); sv += __shfl_xor(sv, o, 64); sr += __shfl_xor(sr, o, 64);
                }
                if (lane == 0) { part[wid][0] = sk; part[wid][1] = sv; part[wid][2] = sr; }
            }
            __syncthreads();
            if ((tid & 127) == 0) {
                float kk = part[wid][0] + part[wid + 1][0];
                float vv = part[wid][1] + part[wid + 1][1];
                float rr = part[wid][2] + part[wid + 1][2];
                int si = ld + c;
                float aa = P.aa[si], bb = P.bb[si], pp = P.pp[si];
                float ww = P.tf[si] + kk;
                float q  = fmaxf(pp, ww);
                float e1 = expf(pp - q), e2 = expf(ww - q);
                float an = e1 * aa + e2 * vv, bn = e1 * bb + e2;
                float ww2 = pp + P.td[si];
                float q2  = fmaxf(ww2, kk);
                float e1b = expf(ww2 - q2), e2b = expf(kk - q2);
                P.aa[si] = e1b * aa + e2b * vv;
                P.bb[si] = e1b * bb + e2b;
                P.pp[si] = q2;
                float sg = 1.f / (1.f + expf(-rr));
                cst(&P.rwkv[c], sg * (an / bn));
            }
            gbar_arrive(P.bar, lsense);
            float pfv = 0.f;
            if (tid < 4 * LPRD) {  // prefetch ow rows into L2
                int rr2 = c0 + tid / LPRD, li = tid % LPRD;
                pfv = ((const float*)(ow + ((long)ld + rr2) * DD))[li * 32];
            }
            gbar_wait(P.bar, lsense);
            pfacc += pfv;

            // ========== stage B: o = ow@rwkv, LIF(v1), x += s ==========
            if (tid < 4) cst(&P.sxa[ld + c0 + tid], xas[c0 + tid]);
            xv[tid]       = cld(&P.rwkv[tid]);          // stage rwkv into LDS
            xv[tid + 512] = cld(&P.rwkv[tid + 512]);
            __syncthreads();
            {
                int base = h * 512 + lane * 8;
                long roff = ((long)ld + c) * DD + base;
                float wf[8], g8[8];
                wload8<WT>(ow, roff, wf);
                ld8(&xv[base], g8);
                float so = dot8(wf, g8);
                #pragma unroll
                for (int o = 32; o; o >>= 1) so += __shfl_xor(so, o, 64);
                if (lane == 0) part[wid][0] = so;
            }
            __syncthreads();
            if ((tid & 127) == 0) {
                float o_ = part[wid][0] + part[wid + 1][0];
                int si = ld + c;
                float v1o = P.v1[si];
                float vn = v1o + (o_ - v1o) * 0.5f;
                float s = (vn >= 1.f) ? 1.f : 0.f;
                P.v1[si] = vn * (1.f - s);
                cst(&P.xg[c], xl[c] + s);
            }
            gbar_arrive(P.bar, lsense);
            pfv = 0.f;
            {   // prefetch fkw (16 rows) + frw (4 rows)
                int tot1 = 16 * LPRD;
                for (int q = tid; q < tot1 + 4 * LPRD; q += NTH) {
                    const float* ad;
                    if (q < tot1) {
                        int j = q / LPRD, li = q % LPRD;
                        int row = (b << 3) + (j & 7) + ((j >> 3) << 11);
                        ad = (const float*)(fkw + ((long)l * FF + row) * DD) + li * 32;
                    } else {
                        int q2 = q - tot1; int rr2 = c0 + q2 / LPRD, li = q2 % LPRD;
                        ad = (const float*)(frw + ((long)ld + rr2) * DD) + li * 32;
                    }
                    pfv += *ad;
                }
            }
            gbar_wait(P.bar, lsense);
            pfacc += pfv;

            // ========== stage C: LN2, mixes, fk/fr dots ==========
            xl[tid] = cld(&P.xg[tid]); xl[tid + 512] = cld(&P.xg[tid + 512]);
            __syncthreads();
            float m2, rs2; bstats(xl, red, m2, rs2);
            for (int i = tid; i < DD; i += NTH) {
                float f = (xl[i] - m2) * rs2 * P.l2w[ld + i] + P.l2b[ld + i];
                xfs[i] = f;
                float sx = cld(&P.sxf[ld + i]);
                float u;
                u = P.ftmk[ld + i]; xk[i] = f * u + sx * (1.f - u);
                u = P.ftmr[ld + i]; xr[i] = f * u + sx * (1.f - u);
            }
            __syncthreads();
            #pragma unroll
            for (int rep = 0; rep < 2; ++rep) {
                int row = (b << 3) + wid + (rep << 11);
                long roff = ((long)l * FF + row) * DD + lane * 16;
                float wf[8], x8[8];
                wload8<WT>(fkw, roff, wf);     ld8(&xk[lane * 16], x8);     float s = dot8(wf, x8);
                wload8<WT>(fkw, roff + 8, wf); ld8(&xk[lane * 16 + 8], x8); s += dot8(wf, x8);
                #pragma unroll
                for (int o = 32; o; o >>= 1) s += __shfl_xor(s, o, 64);
                if (lane == 0) { float r_ = fmaxf(s, 0.f); cst(&P.fk[row], r_ * r_); }
            }
            {
                int base = h * 512 + lane * 8;
                long roff = ((long)ld + c) * DD + base;
                float wf[8], x8[8];
                wload8<WT>(frw, roff, wf); ld8(&xr[base], x8);
                float s = dot8(wf, x8);
                #pragma unroll
                for (int o = 32; o; o >>= 1) s += __shfl_xor(s, o, 64);
                if (lane == 0) part[wid][0] = s;
            }
            __syncthreads();
            if ((tid & 127) == 0) {
                float s = part[wid][0] + part[wid + 1][0];
                frl[wid >> 1] = 1.f / (1.f + expf(-s));   // block-private
            }
            gbar_arrive(P.bar, lsense);
            pfv = 0.f;
            {   // prefetch fvw rows (F-length)
                int LPRF = LPRD * 4;
                for (int q = tid; q < 4 * LPRF; q += NTH) {
                    int rr2 = c0 + q / LPRF, li = q % LPRF;
                    pfv += ((const float*)(fvw + ((long)ld + rr2) * FF))[li * 32];
                }
            }
            gbar_wait(P.bar, lsense);
            pfacc += pfv;

            // ========== stage D: fv = fvw@fk, LIF(v2), x += s, rescale ==========
            if (tid < 4) cst(&P.sxf[ld + c0 + tid], xfs[c0 + tid]);
            #pragma unroll
            for (int j = 0; j < 8; ++j)                     // stage fk into LDS (coalesced)
                fkl[tid + 512 * j] = cld(&P.fk[tid + 512 * j]);
            __syncthreads();
            {
                long roff = ((long)ld + c) * FF + (h << 11) + lane * 32;
                const float* fkp = &fkl[(h << 11) + lane * 32];
                float s = 0.f;
                #pragma unroll
                for (int u2 = 0; u2 < 4; ++u2) {
                    float wf[8], g8[8];
                    wload8<WT>(fvw, roff + u2 * 8, wf);
                    ld8(fkp + u2 * 8, g8);
                    s += dot8(wf, g8);
                }
                #pragma unroll
                for (int o = 32; o; o >>= 1) s += __shfl_xor(s, o, 64);
                if (lane == 0) part[wid][0] = s;
            }
            __syncthreads();
            if ((tid & 127) == 0) {
                float fv = part[wid][0] + part[wid + 1][0];
                float hh = frl[wid >> 1] * fv;
                int si = ld + c;
                float v2o = P.v2[si];
                float vn = v2o + (hh - v2o) * 0.5f;
                float s = (vn >= 1.f) ? 1.f : 0.f;
                P.v2[si] = vn * (1.f - s);
                float xn = xl[c] + s;
                if (((l + 1) % 6) == 0) xn *= 0.5f;
                cst(&P.xg[c], xn);
            }
            gbar_arrive(P.bar, lsense);
            pfv = 0.f;
            {   // prefetch next layer's kw/vw/rw rows
                int lnx = (l + 1) % LL;
                for (int q = tid; q < 12 * LPRD; q += NTH) {
                    int mm = q / (4 * LPRD), q2 = q % (4 * LPRD);
                    int rr2 = c0 + q2 / LPRD, li = q2 % LPRD;
                    const WT* mp = (mm == 0) ? kw : ((mm == 1) ? vw : rw);
                    pfv += ((const float*)(mp + ((long)lnx * DD + rr2) * DD))[li * 32];
                }
            }
            gbar_wait(P.bar, lsense);
            pfacc += pfv;
        }
    }
    if (tid == 0 && pfacc == 1.2345e37f) P.xg[0] = 0.f;  // keep prefetch loads alive
}

// ---------------- VALU head: out[t][v] = sum_k head[v][k]*XbT[k][t] (f32 out) --
__global__ __launch_bounds__(256) void head_simple(const float* __restrict__ head,
                                                   const float* __restrict__ XbT,
                                                   float* __restrict__ out) {
    int wv   = __builtin_amdgcn_readfirstlane(threadIdx.x >> 6);
    int lane = threadIdx.x & 63;
    int v0   = (blockIdx.x * 4 + wv) * 8;
    if (v0 >= VV) return;                      // wave-uniform
    const float* hp[8];
    #pragma unroll
    for (int r = 0; r < 8; ++r) {
        int v = v0 + r; if (v >= VV) v = VV - 1;   // clamp (stores guarded below)
        hp[r] = head + (size_t)v * DD;
    }
    float a0[8], a1[8];
    #pragma unroll
    for (int r = 0; r < 8; ++r) { a0[r] = 0.f; a1[r] = 0.f; }
    #pragma unroll 4
    for (int k = 0; k < DD; ++k) {
        float2 x2 = *(const float2*)(XbT + (size_t)k * TTOK + lane * 2);
        #pragma unroll
        for (int r = 0; r < 8; ++r) {
            float hv = hp[r][k];
            a0[r] += hv * x2.x;
            a1[r] += hv * x2.y;
        }
    }
    int t0 = lane * 2, t1 = t0 + 1;
    #pragma unroll
    for (int r = 0; r < 8; ++r) {
        int v = v0 + r;
        if (v < VV) {
            out[(size_t)t0 * VV + v] = a0[r];
            out[(size_t)t1 * VV + v] = a1[r];
        }
    }
}

// ---------------- fp32 -> bf16 conversion ----------------
__global__ void cvt_bf16(const float* __restrict__ s, unsigned short* __restrict__ d, long n) {
    long i = ((long)blockIdx.x * blockDim.x + threadIdx.x) * 4;
    long st = (long)gridDim.x * blockDim.x * 4;
    for (; i < n; i += st) {
        float4 f = *(const float4*)(s + i);
        ushort4 o;
        o.x = f2bf(f.x); o.y = f2bf(f.y); o.z = f2bf(f.z); o.w = f2bf(f.w);
        *(ushort4*)(d + i) = o;
    }
}

// ---------------- host launch ----------------
extern "C" void kernel_launch(void* const* d_in, const int* in_sizes, int n_in,
                              void* d_out, int out_size, void* d_ws, size_t ws_size,
                              hipStream_t stream) {
    (void)in_sizes; (void)n_in; (void)out_size;
    char* base = (char*)d_ws;
    size_t off = 0;
    auto take = [&](size_t bytes) -> void* {
        void* p = base + off;
        off = (off + bytes + 255) & ~(size_t)255;
        return p;
    };
    unsigned* bar = (unsigned*)take(2048);
    float* xg   = (float*)take(DD * 4);
    float* rwkv = (float*)take(DD * 4);
    float* fk   = (float*)take(FF * 4);
    float* td   = (float*)take(LL * DD * 4);
    float* aa   = (float*)take(LL * DD * 4);
    float* bb   = (float*)take(LL * DD * 4);
    float* pp   = (float*)take(LL * DD * 4);
    float* sxa  = (float*)take(LL * DD * 4);
    float* sxf  = (float*)take(LL * DD * 4);
    float* v1   = (float*)take(LL * DD * 4);
    float* v2   = (float*)take(LL * DD * 4);
    float* XbT  = (float*)take((size_t)DD * TTOK * 4);
    size_t wDD = (size_t)LL * DD * DD;
    size_t wFD = (size_t)LL * FF * DD;
    unsigned short* kwb  = (unsigned short*)take(wDD * 2);
    unsigned short* vwb  = (unsigned short*)take(wDD * 2);
    unsigned short* rwb  = (unsigned short*)take(wDD * 2);
    unsigned short* owb  = (unsigned short*)take(wDD * 2);
    unsigned short* frwb = (unsigned short*)take(wDD * 2);
    unsigned short* fkwb = (unsigned short*)take(wFD * 2);
    unsigned short* fvwb = (unsigned short*)take(wFD * 2);
    bool usebf = (ws_size >= off);

    hipMemsetAsync(bar, 0, 2048, stream);

    SP P;
    P.tok = (const int*)d_in[0];
    P.emb = (const float*)d_in[1];
    P.pos = (const float*)d_in[2];
    P.l0w = (const float*)d_in[3];  P.l0b = (const float*)d_in[4];
    P.l1w = (const float*)d_in[5];  P.l1b = (const float*)d_in[6];
    P.l2w = (const float*)d_in[7];  P.l2b = (const float*)d_in[8];
    P.tmk = (const float*)d_in[9];  P.tmv = (const float*)d_in[10]; P.tmr = (const float*)d_in[11];
    P.tf  = (const float*)d_in[12]; P.tdr = (const float*)d_in[13];
    P.ftmk = (const float*)d_in[18]; P.ftmr = (const float*)d_in[19];
    P.low = (const float*)d_in[23]; P.lob = (const float*)d_in[24];
    P.xg = xg; P.rwkv = rwkv; P.fk = fk; P.td = td;
    P.aa = aa; P.bb = bb; P.pp = pp; P.sxa = sxa; P.sxf = sxf; P.v1 = v1; P.v2 = v2;
    P.XbT = XbT; P.bar = bar;

    if (usebf) {
        struct CV { const float* s; unsigned short* d; size_t n; } cv[7] = {
            {(const float*)d_in[14], kwb,  wDD}, {(const float*)d_in[15], vwb,  wDD},
            {(const float*)d_in[16], rwb,  wDD}, {(const float*)d_in[17], owb,  wDD},
            {(const float*)d_in[22], frwb, wDD},
            {(const float*)d_in[20], fkwb, wFD}, {(const float*)d_in[21], fvwb, wFD},
        };
        for (int i = 0; i < 7; ++i)
            cvt_bf16<<<dim3(2048), dim3(256), 0, stream>>>(cv[i].s, cv[i].d, (long)cv[i].n);
        P.kw = kwb; P.vw = vwb; P.rw = rwb; P.ow = owb; P.fkw = fkwb; P.fvw = fvwb; P.frw = frwb;
        spike_persist<unsigned short><<<dim3(NBLK), dim3(NTH), 0, stream>>>(P);
    } else {
        P.kw = d_in[14]; P.vw = d_in[15]; P.rw = d_in[16]; P.ow = d_in[17];
        P.fkw = d_in[20]; P.fvw = d_in[21]; P.frw = d_in[22];
        spike_persist<float><<<dim3(NBLK), dim3(NTH), 0, stream>>>(P);
    }
    // head: 8 v-rows per wave, 4 waves per block
    int nwave = (VV + 7) / 8;
    int nblk  = (nwave + 3) / 4;
    head_simple<<<dim3(nblk), dim3(256), 0, stream>>>((const float*)d_in[25], XbT,
                                                      (float*)d_out);
}

// Round 5
// 17022.835 us; speedup vs baseline: 17.8064x; 2.3622x over previous
//
#include <hip/hip_runtime.h>
#include <hip/hip_bf16.h>

// ---------------- constants ----------------
#define LL   12
#define DD   1024
#define FF   4096
#define TTOK 128
#define VV   50257
#define NBLK 256
#define NTH  512
#define NGRP 12
#define GBLK 21                 // blocks per layer group (12*21=252, +4 head)
#define NSTEP (TTOK + NGRP)     // 140 wavefront steps

// ---------------- coherent (cross-XCD) access helpers ----------------
__device__ __forceinline__ float cld(const float* p) {
    return __hip_atomic_load((float*)p, __ATOMIC_RELAXED, __HIP_MEMORY_SCOPE_AGENT);
}
__device__ __forceinline__ void cst(float* p, float v) {
    __hip_atomic_store(p, v, __ATOMIC_RELAXED, __HIP_MEMORY_SCOPE_AGENT);
}

// ---------------- small helpers ----------------
__device__ __host__ __forceinline__ unsigned short f2bf(float f) {
    union { float f; unsigned u; } x; x.f = f;
    unsigned r = x.u + 0x7fffu + ((x.u >> 16) & 1u);
    return (unsigned short)(r >> 16);
}

__device__ __forceinline__ unsigned pack_bf2(float a, float b) {
    return (unsigned)f2bf(a) | ((unsigned)f2bf(b) << 16);
}

__device__ __forceinline__ void ld8(const float* p, float* o) {
    float4 a = ((const float4*)p)[0], b = ((const float4*)p)[1];
    o[0]=a.x; o[1]=a.y; o[2]=a.z; o[3]=a.w; o[4]=b.x; o[5]=b.y; o[6]=b.z; o[7]=b.w;
}

__device__ __forceinline__ void bf8unpack(uint4 u, float* o) {
    union { unsigned u; float f; } t;
    t.u = u.x << 16;         o[0] = t.f;
    t.u = u.x & 0xffff0000u; o[1] = t.f;
    t.u = u.y << 16;         o[2] = t.f;
    t.u = u.y & 0xffff0000u; o[3] = t.f;
    t.u = u.z << 16;         o[4] = t.f;
    t.u = u.z & 0xffff0000u; o[5] = t.f;
    t.u = u.w << 16;         o[6] = t.f;
    t.u = u.w & 0xffff0000u; o[7] = t.f;
}

template<typename WT>
__device__ __forceinline__ void wload8e(const WT* w, long elem, float* o) {
    if constexpr (sizeof(WT) == 2) {
        uint4 u = *reinterpret_cast<const uint4*>(
            reinterpret_cast<const unsigned short*>(w) + elem);
        bf8unpack(u, o);
    } else {
        ld8(reinterpret_cast<const float*>(w) + elem, o);
    }
}

// bf16 LDS chunk read: chunk = 16B = 8 elems, lane-stride 16B (bank-friendly)
__device__ __forceinline__ void xld8(const unsigned short* x, int chunk, float* o) {
    uint4 u = *reinterpret_cast<const uint4*>(x + (chunk << 3));
    bf8unpack(u, o);
}

__device__ __forceinline__ float dot8(const float* w, const float* x) {
    return w[0]*x[0]+w[1]*x[1]+w[2]*x[2]+w[3]*x[3]+w[4]*x[4]+w[5]*x[5]+w[6]*x[6]+w[7]*x[7];
}

__device__ __forceinline__ float wred(float s) {
    #pragma unroll
    for (int o = 32; o; o >>= 1) s += __shfl_xor(s, o, 64);
    return s;
}

// full-row dot: row of NCHUNK*512 elems; lane handles chunks {lane + 64m}
template<typename WT, int NCHUNK>
__device__ __forceinline__ float dotrow(const WT* w, long rowbase,
                                        const unsigned short* xb, int lane) {
    float s = 0.f;
    #pragma unroll
    for (int m = 0; m < NCHUNK; ++m) {
        int ch = lane + (m << 6);
        float w8[8], x8[8];
        wload8e<WT>(w, rowbase + ((long)ch << 3), w8);
        xld8(xb, ch, x8);
        s += dot8(w8, x8);
    }
    return s;
}

// block stats over xl[1024] (512 threads): mean + rstd
__device__ __forceinline__ void bstats(const float* xl, float* red, float& m, float& rs) {
    int tid = threadIdx.x;
    float a = xl[tid], b = xl[tid + 512];
    float s0 = a + b, s1 = a*a + b*b;
    #pragma unroll
    for (int o = 32; o; o >>= 1) { s0 += __shfl_xor(s0, o, 64); s1 += __shfl_xor(s1, o, 64); }
    if ((tid & 63) == 0) { red[(tid >> 6) * 2] = s0; red[(tid >> 6) * 2 + 1] = s1; }
    __syncthreads();
    float ms = 0.f, qs = 0.f;
    #pragma unroll
    for (int w = 0; w < 8; ++w) { ms += red[w * 2]; qs += red[w * 2 + 1]; }
    ms *= (1.f / 1024.f); qs *= (1.f / 1024.f);
    m = ms; rs = rsqrtf(qs - ms * ms + 1e-5f);
    __syncthreads();
}

// ---------------- grid barrier: fence-free, two-level, sense-reversing -------
__device__ __forceinline__ void gbar_arrive(unsigned* bar, unsigned lsense) {
    __syncthreads();
    if (threadIdx.x == 0) {
        unsigned s = lsense ^ 1u;
        int g = blockIdx.x >> 5;
        unsigned prev = __hip_atomic_fetch_add(&bar[g * 16], 1u,
                            __ATOMIC_RELAXED, __HIP_MEMORY_SCOPE_AGENT);
        if (prev == 31u) {
            unsigned p2 = __hip_atomic_fetch_add(&bar[128], 1u,
                              __ATOMIC_RELAXED, __HIP_MEMORY_SCOPE_AGENT);
            if (p2 == 7u) {
                #pragma unroll
                for (int i = 0; i < 8; ++i)
                    __hip_atomic_store(&bar[i * 16], 0u, __ATOMIC_RELAXED, __HIP_MEMORY_SCOPE_AGENT);
                __hip_atomic_store(&bar[128], 0u, __ATOMIC_RELAXED, __HIP_MEMORY_SCOPE_AGENT);
                asm volatile("s_waitcnt vmcnt(0)" ::: "memory");
                #pragma unroll
                for (int i = 0; i < 8; ++i)
                    __hip_atomic_store(&bar[160 + i * 16], s, __ATOMIC_RELAXED, __HIP_MEMORY_SCOPE_AGENT);
            }
        }
    }
}

__device__ __forceinline__ void gbar_wait(unsigned* bar, unsigned& lsense) {
    unsigned s = lsense ^ 1u;
    if (threadIdx.x == 0) {
        int g = blockIdx.x >> 5;
        while (__hip_atomic_load(&bar[160 + g * 16], __ATOMIC_RELAXED,
                                 __HIP_MEMORY_SCOPE_AGENT) != s)
            __builtin_amdgcn_s_sleep(4);
    }
    lsense = s;
    __syncthreads();
}

// ---------------- params ----------------
struct SP {
    const int* tok; const float* emb; const float* pos;
    const float *l0w, *l0b, *l1w, *l1b, *l2w, *l2b;
    const float *tmk, *tmv, *tmr, *tf, *tdr;
    const float *ftmk, *ftmr, *low, *lob;
    const void *kw, *vw, *rw, *ow, *fkw, *fvw, *frw;
    float *xg, *xmid, *rwkv, *fk, *td;
    float *aa, *bb, *pp, *sxa, *sxf, *v1, *v2;
    float* XbT;          // [DD][TTOK]
    unsigned* bar;
};

// ---------------- layer-wavefront persistent kernel ----------------
// groups 0..11 = layers (21 blocks each, blocks 0..251); blocks 252..255 = head
// step s: group l works on token t = s - l; head works on token s - 12.
// 4 global barriers per step; cross-group handoff via lockstep ordering.
template<typename WT>
__global__ __launch_bounds__(NTH) void spike_wave(SP P) {
    const WT* kw  = (const WT*)P.kw;
    const WT* vw  = (const WT*)P.vw;
    const WT* rw  = (const WT*)P.rw;
    const WT* ow  = (const WT*)P.ow;
    const WT* fkw = (const WT*)P.fkw;
    const WT* fvw = (const WT*)P.fvw;
    const WT* frw = (const WT*)P.frw;

    __shared__ float xl[DD], xas[DD], xfs[DD];
    __shared__ __align__(16) unsigned short xkb[DD], xvb[DD], xrb[DD];
    __shared__ __align__(16) unsigned short fklb[FF];
    __shared__ float red[16];
    __shared__ float frl[64];

    const int tid  = threadIdx.x;
    const int b    = blockIdx.x;
    const int wid  = tid >> 6;
    const int lane = tid & 63;
    const bool isHead = (b >= NGRP * GBLK);
    const int grp = isHead ? NGRP : (b / GBLK);
    const int gi  = isHead ? (b - NGRP * GBLK) : (b % GBLK);
    int c_beg = 0, c_end = 0, r_beg = 0, r_end = 0;
    if (!isHead) {
        c_beg = (gi * DD) / GBLK; c_end = ((gi + 1) * DD) / GBLK;
        r_beg = (gi * FF) / GBLK; r_end = ((gi + 1) * FF) / GBLK;
    }
    const int  ld = (isHead ? 0 : grp) * DD;
    const long gf = (long)(isHead ? 0 : grp) * FF;

    unsigned lsense = 0;

    // ---- init own layer state ----
    if (!isHead) {
        for (int c = c_beg + tid; c < c_end; c += NTH) {
            int si = ld + c;
            P.aa[si] = 0.f; P.bb[si] = 0.f; P.pp[si] = -1e30f;
            P.v1[si] = 0.f; P.v2[si] = 0.f;
            P.td[si] = -expf(P.tdr[si]);
            cst(&P.sxa[si], 0.f); cst(&P.sxf[si], 0.f);
        }
    }
    gbar_arrive(P.bar, lsense); gbar_wait(P.bar, lsense);

    #pragma unroll 1
    for (int s = 0; s < NSTEP; ++s) {
        const int t = s - grp;                 // grp==NGRP -> head token
        const bool act = (t >= 0) && (t < TTOK);

        // ================= stage A =================
        if (act) {
            if (isHead) {
                xl[tid]       = cld(&P.xg[11 * DD + tid]);
                xl[tid + 512] = cld(&P.xg[11 * DD + tid + 512]);
                __syncthreads();
                float m, rs; bstats(xl, red, m, rs);
                for (int cc = (gi << 8) + tid; cc < ((gi + 1) << 8); cc += NTH)
                    P.XbT[(size_t)cc * TTOK + t] = (xl[cc] - m) * rs * P.low[cc] + P.lob[cc];
            } else {
                if (grp == 0) {
                    int tk = P.tok[t];
                    float e0 = P.emb[(size_t)tk * DD + tid]       + P.pos[(size_t)t * DD + tid];
                    float e1 = P.emb[(size_t)tk * DD + tid + 512] + P.pos[(size_t)t * DD + tid + 512];
                    xl[tid] = e0; xl[tid + 512] = e1;
                    __syncthreads();
                    float m, rs; bstats(xl, red, m, rs);
                    xl[tid]       = (e0 - m) * rs * P.l0w[tid]       + P.l0b[tid];
                    xl[tid + 512] = (e1 - m) * rs * P.l0w[tid + 512] + P.l0b[tid + 512];
                    __syncthreads();
                } else {
                    xl[tid]       = cld(&P.xg[(grp - 1) * DD + tid]);
                    xl[tid + 512] = cld(&P.xg[(grp - 1) * DD + tid + 512]);
                    __syncthreads();
                }
                float m1, rs1; bstats(xl, red, m1, rs1);
                {   // LN1 + mixes (thread handles elems 2tid, 2tid+1)
                    int i2 = tid << 1;
                    float2 w2 = *(const float2*)&P.l1w[ld + i2];
                    float2 b2 = *(const float2*)&P.l1b[ld + i2];
                    float a0 = (xl[i2]     - m1) * rs1 * w2.x + b2.x;
                    float a1 = (xl[i2 + 1] - m1) * rs1 * w2.y + b2.y;
                    xas[i2] = a0; xas[i2 + 1] = a1;
                    float sx0 = cld(&P.sxa[ld + i2]), sx1 = cld(&P.sxa[ld + i2 + 1]);
                    float2 u2;
                    u2 = *(const float2*)&P.tmk[ld + i2];
                    ((unsigned*)xkb)[tid] = pack_bf2(a0*u2.x + sx0*(1.f-u2.x), a1*u2.y + sx1*(1.f-u2.y));
                    u2 = *(const float2*)&P.tmv[ld + i2];
                    ((unsigned*)xvb)[tid] = pack_bf2(a0*u2.x + sx0*(1.f-u2.x), a1*u2.y + sx1*(1.f-u2.y));
                    u2 = *(const float2*)&P.tmr[ld + i2];
                    ((unsigned*)xrb)[tid] = pack_bf2(a0*u2.x + sx0*(1.f-u2.x), a1*u2.y + sx1*(1.f-u2.y));
                }
                __syncthreads();
                for (int c = c_beg + wid; c < c_end; c += 8) {
                    long rb = ((long)ld + c) * DD;
                    float sk = wred(dotrow<WT, 2>(kw, rb, xkb, lane));
                    float sv = wred(dotrow<WT, 2>(vw, rb, xvb, lane));
                    float sr = wred(dotrow<WT, 2>(rw, rb, xrb, lane));
                    if (lane == 0) {
                        int si = ld + c;
                        float aa = P.aa[si], bb = P.bb[si], pp = P.pp[si];
                        float ww = P.tf[si] + sk;
                        float q  = fmaxf(pp, ww);
                        float e1 = expf(pp - q), e2 = expf(ww - q);
                        float an = e1 * aa + e2 * sv, bn = e1 * bb + e2;
                        float ww2 = pp + P.td[si];
                        float q2  = fmaxf(ww2, sk);
                        float e1b = expf(ww2 - q2), e2b = expf(sk - q2);
                        P.aa[si] = e1b * aa + e2b * sv;
                        P.bb[si] = e1b * bb + e2b;
                        P.pp[si] = q2;
                        float sg = 1.f / (1.f + expf(-sr));
                        cst(&P.rwkv[ld + c], sg * (an / bn));
                    }
                }
            }
        }
        gbar_arrive(P.bar, lsense); gbar_wait(P.bar, lsense);

        // ================= stage B =================
        if (act && !isHead) {
            for (int c = c_beg + tid; c < c_end; c += NTH)
                cst(&P.sxa[ld + c], xas[c]);
            {   // stage rwkv -> xvb (bf16)
                int i2 = tid << 1;
                ((unsigned*)xvb)[tid] = pack_bf2(cld(&P.rwkv[ld + i2]),
                                                 cld(&P.rwkv[ld + i2 + 1]));
            }
            __syncthreads();
            for (int c = c_beg + wid; c < c_end; c += 8) {
                long rb = ((long)ld + c) * DD;
                float so = wred(dotrow<WT, 2>(ow, rb, xvb, lane));
                if (lane == 0) {
                    int si = ld + c;
                    float v1o = P.v1[si];
                    float vn = v1o + (so - v1o) * 0.5f;
                    float sp = (vn >= 1.f) ? 1.f : 0.f;
                    P.v1[si] = vn * (1.f - sp);
                    cst(&P.xmid[ld + c], xl[c] + sp);
                }
            }
        }
        gbar_arrive(P.bar, lsense); gbar_wait(P.bar, lsense);

        // ================= stage C =================
        if (act && !isHead) {
            xl[tid]       = cld(&P.xmid[ld + tid]);
            xl[tid + 512] = cld(&P.xmid[ld + tid + 512]);
            __syncthreads();
            float m2, rs2; bstats(xl, red, m2, rs2);
            {   // LN2 + FFN mixes
                int i2 = tid << 1;
                float2 w2 = *(const float2*)&P.l2w[ld + i2];
                float2 b2 = *(const float2*)&P.l2b[ld + i2];
                float f0 = (xl[i2]     - m2) * rs2 * w2.x + b2.x;
                float f1 = (xl[i2 + 1] - m2) * rs2 * w2.y + b2.y;
                xfs[i2] = f0; xfs[i2 + 1] = f1;
                float sx0 = cld(&P.sxf[ld + i2]), sx1 = cld(&P.sxf[ld + i2 + 1]);
                float2 u2;
                u2 = *(const float2*)&P.ftmk[ld + i2];
                ((unsigned*)xkb)[tid] = pack_bf2(f0*u2.x + sx0*(1.f-u2.x), f1*u2.y + sx1*(1.f-u2.y));
                u2 = *(const float2*)&P.ftmr[ld + i2];
                ((unsigned*)xrb)[tid] = pack_bf2(f0*u2.x + sx0*(1.f-u2.x), f1*u2.y + sx1*(1.f-u2.y));
            }
            __syncthreads();
            for (int r = r_beg + wid; r < r_end; r += 8) {
                long rb = (gf + r) * DD;
                float sfk = wred(dotrow<WT, 2>(fkw, rb, xkb, lane));
                if (lane == 0) { float rr = fmaxf(sfk, 0.f); cst(&P.fk[gf + r], rr * rr); }
            }
            for (int c = c_beg + wid; c < c_end; c += 8) {
                long rb = ((long)ld + c) * DD;
                float sfr = wred(dotrow<WT, 2>(frw, rb, xrb, lane));
                if (lane == 0) frl[c - c_beg] = 1.f / (1.f + expf(-sfr));
            }
        }
        gbar_arrive(P.bar, lsense); gbar_wait(P.bar, lsense);

        // ================= stage D =================
        if (act && !isHead) {
            for (int c = c_beg + tid; c < c_end; c += NTH)
                cst(&P.sxf[ld + c], xfs[c]);
            #pragma unroll
            for (int j = 0; j < 4; ++j) {   // stage fk -> fklb (bf16, conflict-free)
                int e = (tid << 1) + (j << 10);
                ((unsigned*)fklb)[tid + (j << 9)] =
                    pack_bf2(cld(&P.fk[gf + e]), cld(&P.fk[gf + e + 1]));
            }
            __syncthreads();
            for (int c = c_beg + wid; c < c_end; c += 8) {
                long rb = ((long)ld + c) * FF;
                float fv = wred(dotrow<WT, 8>(fvw, rb, fklb, lane));
                float hh = frl[c - c_beg] * fv;
                if (lane == 0) {
                    int si = ld + c;
                    float v2o = P.v2[si];
                    float vn = v2o + (hh - v2o) * 0.5f;
                    float sp = (vn >= 1.f) ? 1.f : 0.f;
                    P.v2[si] = vn * (1.f - sp);
                    float xn = xl[c] + sp;
                    if (((grp + 1) % 6) == 0) xn *= 0.5f;
                    cst(&P.xg[ld + c], xn);
                }
            }
        }
        gbar_arrive(P.bar, lsense); gbar_wait(P.bar, lsense);
    }
}

// ---------------- VALU head: out[t][v] = sum_k head[v][k]*XbT[k][t] (f32 out) --
__global__ __launch_bounds__(256) void head_simple(const float* __restrict__ head,
                                                   const float* __restrict__ XbT,
                                                   float* __restrict__ out) {
    int wv   = __builtin_amdgcn_readfirstlane(threadIdx.x >> 6);
    int lane = threadIdx.x & 63;
    int v0   = (blockIdx.x * 4 + wv) * 8;
    if (v0 >= VV) return;
    const float* hp[8];
    #pragma unroll
    for (int r = 0; r < 8; ++r) {
        int v = v0 + r; if (v >= VV) v = VV - 1;
        hp[r] = head + (size_t)v * DD;
    }
    float a0[8], a1[8];
    #pragma unroll
    for (int r = 0; r < 8; ++r) { a0[r] = 0.f; a1[r] = 0.f; }
    #pragma unroll 4
    for (int k = 0; k < DD; ++k) {
        float2 x2 = *(const float2*)(XbT + (size_t)k * TTOK + lane * 2);
        #pragma unroll
        for (int r = 0; r < 8; ++r) {
            float hv = hp[r][k];
            a0[r] += hv * x2.x;
            a1[r] += hv * x2.y;
        }
    }
    int t0 = lane * 2, t1 = t0 + 1;
    #pragma unroll
    for (int r = 0; r < 8; ++r) {
        int v = v0 + r;
        if (v < VV) {
            out[(size_t)t0 * VV + v] = a0[r];
            out[(size_t)t1 * VV + v] = a1[r];
        }
    }
}

// ---------------- fp32 -> bf16 conversion ----------------
__global__ void cvt_bf16(const float* __restrict__ s, unsigned short* __restrict__ d, long n) {
    long i = ((long)blockIdx.x * blockDim.x + threadIdx.x) * 4;
    long st = (long)gridDim.x * blockDim.x * 4;
    for (; i < n; i += st) {
        float4 f = *(const float4*)(s + i);
        ushort4 o;
        o.x = f2bf(f.x); o.y = f2bf(f.y); o.z = f2bf(f.z); o.w = f2bf(f.w);
        *(ushort4*)(d + i) = o;
    }
}

// ---------------- host launch ----------------
extern "C" void kernel_launch(void* const* d_in, const int* in_sizes, int n_in,
                              void* d_out, int out_size, void* d_ws, size_t ws_size,
                              hipStream_t stream) {
    (void)in_sizes; (void)n_in; (void)out_size;
    char* base = (char*)d_ws;
    size_t off = 0;
    auto take = [&](size_t bytes) -> void* {
        void* p = base + off;
        off = (off + bytes + 255) & ~(size_t)255;
        return p;
    };
    unsigned* bar = (unsigned*)take(2048);
    float* xg   = (float*)take((size_t)NGRP * DD * 4);
    float* xmid = (float*)take((size_t)NGRP * DD * 4);
    float* rwkv = (float*)take((size_t)NGRP * DD * 4);
    float* fk   = (float*)take((size_t)NGRP * FF * 4);
    float* td   = (float*)take(LL * DD * 4);
    float* aa   = (float*)take(LL * DD * 4);
    float* bb   = (float*)take(LL * DD * 4);
    float* pp   = (float*)take(LL * DD * 4);
    float* sxa  = (float*)take(LL * DD * 4);
    float* sxf  = (float*)take(LL * DD * 4);
    float* v1   = (float*)take(LL * DD * 4);
    float* v2   = (float*)take(LL * DD * 4);
    float* XbT  = (float*)take((size_t)DD * TTOK * 4);
    size_t wDD = (size_t)LL * DD * DD;
    size_t wFD = (size_t)LL * FF * DD;
    unsigned short* kwb  = (unsigned short*)take(wDD * 2);
    unsigned short* vwb  = (unsigned short*)take(wDD * 2);
    unsigned short* rwb  = (unsigned short*)take(wDD * 2);
    unsigned short* owb  = (unsigned short*)take(wDD * 2);
    unsigned short* frwb = (unsigned short*)take(wDD * 2);
    unsigned short* fkwb = (unsigned short*)take(wFD * 2);
    unsigned short* fvwb = (unsigned short*)take(wFD * 2);
    bool usebf = (ws_size >= off);

    hipMemsetAsync(bar, 0, 2048, stream);

    SP P;
    P.tok = (const int*)d_in[0];
    P.emb = (const float*)d_in[1];
    P.pos = (const float*)d_in[2];
    P.l0w = (const float*)d_in[3];  P.l0b = (const float*)d_in[4];
    P.l1w = (const float*)d_in[5];  P.l1b = (const float*)d_in[6];
    P.l2w = (const float*)d_in[7];  P.l2b = (const float*)d_in[8];
    P.tmk = (const float*)d_in[9];  P.tmv = (const float*)d_in[10]; P.tmr = (const float*)d_in[11];
    P.tf  = (const float*)d_in[12]; P.tdr = (const float*)d_in[13];
    P.ftmk = (const float*)d_in[18]; P.ftmr = (const float*)d_in[19];
    P.low = (const float*)d_in[23]; P.lob = (const float*)d_in[24];
    P.xg = xg; P.xmid = xmid; P.rwkv = rwkv; P.fk = fk; P.td = td;
    P.aa = aa; P.bb = bb; P.pp = pp; P.sxa = sxa; P.sxf = sxf; P.v1 = v1; P.v2 = v2;
    P.XbT = XbT; P.bar = bar;

    if (usebf) {
        struct CV { const float* s; unsigned short* d; size_t n; } cv[7] = {
            {(const float*)d_in[14], kwb,  wDD}, {(const float*)d_in[15], vwb,  wDD},
            {(const float*)d_in[16], rwb,  wDD}, {(const float*)d_in[17], owb,  wDD},
            {(const float*)d_in[22], frwb, wDD},
            {(const float*)d_in[20], fkwb, wFD}, {(const float*)d_in[21], fvwb, wFD},
        };
        for (int i = 0; i < 7; ++i)
            cvt_bf16<<<dim3(2048), dim3(256), 0, stream>>>(cv[i].s, cv[i].d, (long)cv[i].n);
        P.kw = kwb; P.vw = vwb; P.rw = rwb; P.ow = owb; P.fkw = fkwb; P.fvw = fvwb; P.frw = frwb;
        spike_wave<unsigned short><<<dim3(NBLK), dim3(NTH), 0, stream>>>(P);
    } else {
        P.kw = d_in[14]; P.vw = d_in[15]; P.rw = d_in[16]; P.ow = d_in[17];
        P.fkw = d_in[20]; P.fvw = d_in[21]; P.frw = d_in[22];
        spike_wave<float><<<dim3(NBLK), dim3(NTH), 0, stream>>>(P);
    }
    int nwave = (VV + 7) / 8;
    int nblk  = (nwave + 3) / 4;
    head_simple<<<dim3(nblk), dim3(256), 0, stream>>>((const float*)d_in[25], XbT,
                                                      (float*)d_out);
}

// Round 6
// 13716.202 us; speedup vs baseline: 22.0991x; 1.2411x over previous
//
#include <hip/hip_runtime.h>
#include <hip/hip_bf16.h>

// ---------------- constants ----------------
#define LL   12
#define DD   1024
#define FF   4096
#define TTOK 128
#define VV   50257
#define NBLK 512
#define NTH  512
#define NGRP 12
#define GBLK 42                 // blocks per layer group (12*42=504, +8 head)
#define NHEADB (NBLK - NGRP * GBLK)
#define NGB  (NBLK / 32)        // barrier leaf groups = 16
#define NSTEP (TTOK + NGRP)     // 140 wavefront steps

// ---------------- coherent (cross-XCD) access helpers ----------------
__device__ __forceinline__ float cld(const float* p) {
    return __hip_atomic_load((float*)p, __ATOMIC_RELAXED, __HIP_MEMORY_SCOPE_AGENT);
}
__device__ __forceinline__ void cst(float* p, float v) {
    __hip_atomic_store(p, v, __ATOMIC_RELAXED, __HIP_MEMORY_SCOPE_AGENT);
}

// ---------------- small helpers ----------------
__device__ __host__ __forceinline__ unsigned short f2bf(float f) {
    union { float f; unsigned u; } x; x.f = f;
    unsigned r = x.u + 0x7fffu + ((x.u >> 16) & 1u);
    return (unsigned short)(r >> 16);
}

__device__ __forceinline__ unsigned pack_bf2(float a, float b) {
    return (unsigned)f2bf(a) | ((unsigned)f2bf(b) << 16);
}

__device__ __forceinline__ void ld8(const float* p, float* o) {
    float4 a = ((const float4*)p)[0], b = ((const float4*)p)[1];
    o[0]=a.x; o[1]=a.y; o[2]=a.z; o[3]=a.w; o[4]=b.x; o[5]=b.y; o[6]=b.z; o[7]=b.w;
}

__device__ __forceinline__ void bf8unpack(uint4 u, float* o) {
    union { unsigned u; float f; } t;
    t.u = u.x << 16;         o[0] = t.f;
    t.u = u.x & 0xffff0000u; o[1] = t.f;
    t.u = u.y << 16;         o[2] = t.f;
    t.u = u.y & 0xffff0000u; o[3] = t.f;
    t.u = u.z << 16;         o[4] = t.f;
    t.u = u.z & 0xffff0000u; o[5] = t.f;
    t.u = u.w << 16;         o[6] = t.f;
    t.u = u.w & 0xffff0000u; o[7] = t.f;
}

template<typename WT>
__device__ __forceinline__ void wload8e(const WT* w, long elem, float* o) {
    if constexpr (sizeof(WT) == 2) {
        uint4 u = *reinterpret_cast<const uint4*>(
            reinterpret_cast<const unsigned short*>(w) + elem);
        bf8unpack(u, o);
    } else {
        ld8(reinterpret_cast<const float*>(w) + elem, o);
    }
}

// bf16 LDS chunk read: chunk = 16B = 8 elems, lane-stride 16B (bank-friendly)
__device__ __forceinline__ void xld8(const unsigned short* x, int chunk, float* o) {
    uint4 u = *reinterpret_cast<const uint4*>(x + (chunk << 3));
    bf8unpack(u, o);
}

__device__ __forceinline__ float dot8(const float* w, const float* x) {
    return w[0]*x[0]+w[1]*x[1]+w[2]*x[2]+w[3]*x[3]+w[4]*x[4]+w[5]*x[5]+w[6]*x[6]+w[7]*x[7];
}

__device__ __forceinline__ float wred(float s) {
    #pragma unroll
    for (int o = 32; o; o >>= 1) s += __shfl_xor(s, o, 64);
    return s;
}

// full-row dot partial: row of NCHUNK*512 elems; lane handles chunks {lane+64m}
template<typename WT, int NCHUNK>
__device__ __forceinline__ float dotrow(const WT* w, long rowbase,
                                        const unsigned short* xb, int lane) {
    float s = 0.f;
    #pragma unroll
    for (int m = 0; m < NCHUNK; ++m) {
        int ch = lane + (m << 6);
        float w8[8], x8[8];
        wload8e<WT>(w, rowbase + ((long)ch << 3), w8);
        xld8(xb, ch, x8);
        s += dot8(w8, x8);
    }
    return s;
}

// block stats over xl[1024] (512 threads): mean + rstd
__device__ __forceinline__ void bstats(const float* xl, float* red, float& m, float& rs) {
    int tid = threadIdx.x;
    float a = xl[tid], b = xl[tid + 512];
    float s0 = a + b, s1 = a*a + b*b;
    #pragma unroll
    for (int o = 32; o; o >>= 1) { s0 += __shfl_xor(s0, o, 64); s1 += __shfl_xor(s1, o, 64); }
    if ((tid & 63) == 0) { red[(tid >> 6) * 2] = s0; red[(tid >> 6) * 2 + 1] = s1; }
    __syncthreads();
    float ms = 0.f, qs = 0.f;
    #pragma unroll
    for (int w = 0; w < 8; ++w) { ms += red[w * 2]; qs += red[w * 2 + 1]; }
    ms *= (1.f / 1024.f); qs *= (1.f / 1024.f);
    m = ms; rs = rsqrtf(qs - ms * ms + 1e-5f);
    __syncthreads();
}

// ---------------- grid barrier: fence-free, two-level, sense-reversing -------
// bar layout (uints): bar[g*16] g<NGB leaf counters; bar[256] root;
//                     bar[288 + g*16] per-group sense copies.
__device__ __forceinline__ void gbar_arrive(unsigned* bar, unsigned lsense) {
    __syncthreads();
    if (threadIdx.x == 0) {
        unsigned s = lsense ^ 1u;
        int g = blockIdx.x >> 5;
        unsigned prev = __hip_atomic_fetch_add(&bar[g * 16], 1u,
                            __ATOMIC_RELAXED, __HIP_MEMORY_SCOPE_AGENT);
        if (prev == 31u) {
            unsigned p2 = __hip_atomic_fetch_add(&bar[256], 1u,
                              __ATOMIC_RELAXED, __HIP_MEMORY_SCOPE_AGENT);
            if (p2 == (unsigned)(NGB - 1)) {
                #pragma unroll
                for (int i = 0; i < NGB; ++i)
                    __hip_atomic_store(&bar[i * 16], 0u, __ATOMIC_RELAXED, __HIP_MEMORY_SCOPE_AGENT);
                __hip_atomic_store(&bar[256], 0u, __ATOMIC_RELAXED, __HIP_MEMORY_SCOPE_AGENT);
                asm volatile("s_waitcnt vmcnt(0)" ::: "memory");
                #pragma unroll
                for (int i = 0; i < NGB; ++i)
                    __hip_atomic_store(&bar[288 + i * 16], s, __ATOMIC_RELAXED, __HIP_MEMORY_SCOPE_AGENT);
            }
        }
    }
}

__device__ __forceinline__ void gbar_wait(unsigned* bar, unsigned& lsense) {
    unsigned s = lsense ^ 1u;
    if (threadIdx.x == 0) {
        int g = blockIdx.x >> 5;
        while (__hip_atomic_load(&bar[288 + g * 16], __ATOMIC_RELAXED,
                                 __HIP_MEMORY_SCOPE_AGENT) != s)
            __builtin_amdgcn_s_sleep(4);
    }
    lsense = s;
    __syncthreads();
}

// ---------------- params ----------------
struct SP {
    const int* tok; const float* emb; const float* pos;
    const float *l0w, *l0b, *l1w, *l1b, *l2w, *l2b;
    const float *tmk, *tmv, *tmr, *tf, *tdr;
    const float *ftmk, *ftmr, *low, *lob;
    const void *kw, *vw, *rw, *ow, *fkw, *fvw, *frw;
    float *xg, *xmid, *rwkv, *fk, *td;
    float *aa, *bb, *pp, *sxa, *sxf, *v1, *v2;
    float* XbT;          // [DD][TTOK]
    unsigned* bar;
};

// ---------------- layer-wavefront persistent kernel ----------------
// groups 0..11 = layers (42 blocks each, blocks 0..503); blocks 504..511 = head
// step s: group l works on token t = s - l; head works on token s - 12.
template<typename WT>
__global__ __launch_bounds__(NTH, 4) void spike_wave(SP P) {
    const WT* kw  = (const WT*)P.kw;
    const WT* vw  = (const WT*)P.vw;
    const WT* rw  = (const WT*)P.rw;
    const WT* ow  = (const WT*)P.ow;
    const WT* fkw = (const WT*)P.fkw;
    const WT* fvw = (const WT*)P.fvw;
    const WT* frw = (const WT*)P.frw;

    __shared__ float xl[DD], xas[DD], xfs[DD];
    __shared__ __align__(16) unsigned short xkb[DD], xvb[DD], xrb[DD];
    __shared__ __align__(16) unsigned short fklb[FF];
    __shared__ float red[16];
    __shared__ float frl[32];

    const int tid  = threadIdx.x;
    const int b    = blockIdx.x;
    const int wid  = tid >> 6;
    const int lane = tid & 63;
    const bool isHead = (b >= NGRP * GBLK);
    const int grp = isHead ? NGRP : (b / GBLK);
    const int gi  = isHead ? (b - NGRP * GBLK) : (b % GBLK);
    int c_beg = 0, c_end = 0, r_beg = 0, r_end = 0;
    if (!isHead) {
        c_beg = (gi * DD) / GBLK; c_end = ((gi + 1) * DD) / GBLK;
        r_beg = (gi * FF) / GBLK; r_end = ((gi + 1) * FF) / GBLK;
    }
    const int  ld = (isHead ? 0 : grp) * DD;
    const long gf = (long)(isHead ? 0 : grp) * FF;

    unsigned lsense = 0;

    // ---- init own layer state ----
    if (!isHead) {
        for (int c = c_beg + tid; c < c_end; c += NTH) {
            int si = ld + c;
            P.aa[si] = 0.f; P.bb[si] = 0.f; P.pp[si] = -1e30f;
            P.v1[si] = 0.f; P.v2[si] = 0.f;
            P.td[si] = -expf(P.tdr[si]);
            cst(&P.sxa[si], 0.f); cst(&P.sxf[si], 0.f);
        }
    }
    gbar_arrive(P.bar, lsense); gbar_wait(P.bar, lsense);

    #pragma unroll 1
    for (int s = 0; s < NSTEP; ++s) {
        const int t = s - grp;                 // grp==NGRP -> head token
        const bool act = (t >= 0) && (t < TTOK);

        // ================= stage A =================
        if (act) {
            if (isHead) {
                xl[tid]       = cld(&P.xg[11 * DD + tid]);
                xl[tid + 512] = cld(&P.xg[11 * DD + tid + 512]);
                __syncthreads();
                float m, rs; bstats(xl, red, m, rs);
                for (int cc = (gi << 7) + tid; cc < ((gi + 1) << 7); cc += NTH)
                    P.XbT[(size_t)cc * TTOK + t] = (xl[cc] - m) * rs * P.low[cc] + P.lob[cc];
            } else {
                if (grp == 0) {
                    int tk = P.tok[t];
                    float e0 = P.emb[(size_t)tk * DD + tid]       + P.pos[(size_t)t * DD + tid];
                    float e1 = P.emb[(size_t)tk * DD + tid + 512] + P.pos[(size_t)t * DD + tid + 512];
                    xl[tid] = e0; xl[tid + 512] = e1;
                    __syncthreads();
                    float m, rs; bstats(xl, red, m, rs);
                    xl[tid]       = (e0 - m) * rs * P.l0w[tid]       + P.l0b[tid];
                    xl[tid + 512] = (e1 - m) * rs * P.l0w[tid + 512] + P.l0b[tid + 512];
                    __syncthreads();
                } else {
                    xl[tid]       = cld(&P.xg[(grp - 1) * DD + tid]);
                    xl[tid + 512] = cld(&P.xg[(grp - 1) * DD + tid + 512]);
                    __syncthreads();
                }
                float m1, rs1; bstats(xl, red, m1, rs1);
                {   // LN1 + mixes (thread handles elems 2tid, 2tid+1)
                    int i2 = tid << 1;
                    float2 w2 = *(const float2*)&P.l1w[ld + i2];
                    float2 b2 = *(const float2*)&P.l1b[ld + i2];
                    float a0 = (xl[i2]     - m1) * rs1 * w2.x + b2.x;
                    float a1 = (xl[i2 + 1] - m1) * rs1 * w2.y + b2.y;
                    xas[i2] = a0; xas[i2 + 1] = a1;
                    float sx0 = cld(&P.sxa[ld + i2]), sx1 = cld(&P.sxa[ld + i2 + 1]);
                    float2 u2;
                    u2 = *(const float2*)&P.tmk[ld + i2];
                    ((unsigned*)xkb)[tid] = pack_bf2(a0*u2.x + sx0*(1.f-u2.x), a1*u2.y + sx1*(1.f-u2.y));
                    u2 = *(const float2*)&P.tmv[ld + i2];
                    ((unsigned*)xvb)[tid] = pack_bf2(a0*u2.x + sx0*(1.f-u2.x), a1*u2.y + sx1*(1.f-u2.y));
                    u2 = *(const float2*)&P.tmr[ld + i2];
                    ((unsigned*)xrb)[tid] = pack_bf2(a0*u2.x + sx0*(1.f-u2.x), a1*u2.y + sx1*(1.f-u2.y));
                }
                __syncthreads();
                for (int c = c_beg + wid; c < c_end; c += 8) {
                    long rb = ((long)ld + c) * DD;
                    // issue all 6 load batches before any shuffle chain
                    float pk = dotrow<WT, 2>(kw, rb, xkb, lane);
                    float pv = dotrow<WT, 2>(vw, rb, xvb, lane);
                    float pr = dotrow<WT, 2>(rw, rb, xrb, lane);
                    float sk = wred(pk), sv = wred(pv), sr = wred(pr);
                    if (lane == 0) {
                        int si = ld + c;
                        float aa = P.aa[si], bb = P.bb[si], pp = P.pp[si];
                        float ww = P.tf[si] + sk;
                        float q  = fmaxf(pp, ww);
                        float e1 = expf(pp - q), e2 = expf(ww - q);
                        float an = e1 * aa + e2 * sv, bn = e1 * bb + e2;
                        float ww2 = pp + P.td[si];
                        float q2  = fmaxf(ww2, sk);
                        float e1b = expf(ww2 - q2), e2b = expf(sk - q2);
                        P.aa[si] = e1b * aa + e2b * sv;
                        P.bb[si] = e1b * bb + e2b;
                        P.pp[si] = q2;
                        float sg = 1.f / (1.f + expf(-sr));
                        cst(&P.rwkv[ld + c], sg * (an / bn));
                    }
                }
            }
        }
        gbar_arrive(P.bar, lsense); gbar_wait(P.bar, lsense);

        // ================= stage B =================
        if (act && !isHead) {
            for (int c = c_beg + tid; c < c_end; c += NTH)
                cst(&P.sxa[ld + c], xas[c]);
            {   // stage rwkv -> xvb (bf16)
                int i2 = tid << 1;
                ((unsigned*)xvb)[tid] = pack_bf2(cld(&P.rwkv[ld + i2]),
                                                 cld(&P.rwkv[ld + i2 + 1]));
            }
            __syncthreads();
            for (int c = c_beg + wid; c < c_end; c += 8) {
                long rb = ((long)ld + c) * DD;
                float so = wred(dotrow<WT, 2>(ow, rb, xvb, lane));
                if (lane == 0) {
                    int si = ld + c;
                    float v1o = P.v1[si];
                    float vn = v1o + (so - v1o) * 0.5f;
                    float sp = (vn >= 1.f) ? 1.f : 0.f;
                    P.v1[si] = vn * (1.f - sp);
                    cst(&P.xmid[ld + c], xl[c] + sp);
                }
            }
        }
        gbar_arrive(P.bar, lsense); gbar_wait(P.bar, lsense);

        // ================= stage C =================
        if (act && !isHead) {
            xl[tid]       = cld(&P.xmid[ld + tid]);
            xl[tid + 512] = cld(&P.xmid[ld + tid + 512]);
            __syncthreads();
            float m2, rs2; bstats(xl, red, m2, rs2);
            {   // LN2 + FFN mixes
                int i2 = tid << 1;
                float2 w2 = *(const float2*)&P.l2w[ld + i2];
                float2 b2 = *(const float2*)&P.l2b[ld + i2];
                float f0 = (xl[i2]     - m2) * rs2 * w2.x + b2.x;
                float f1 = (xl[i2 + 1] - m2) * rs2 * w2.y + b2.y;
                xfs[i2] = f0; xfs[i2 + 1] = f1;
                float sx0 = cld(&P.sxf[ld + i2]), sx1 = cld(&P.sxf[ld + i2 + 1]);
                float2 u2;
                u2 = *(const float2*)&P.ftmk[ld + i2];
                ((unsigned*)xkb)[tid] = pack_bf2(f0*u2.x + sx0*(1.f-u2.x), f1*u2.y + sx1*(1.f-u2.y));
                u2 = *(const float2*)&P.ftmr[ld + i2];
                ((unsigned*)xrb)[tid] = pack_bf2(f0*u2.x + sx0*(1.f-u2.x), f1*u2.y + sx1*(1.f-u2.y));
            }
            __syncthreads();
            // fkw rows: 2-row software pipeline for doubled loads-in-flight
            for (int r = r_beg + wid; r < r_end; r += 16) {
                int r1 = r + 8;
                float p0 = dotrow<WT, 2>(fkw, (gf + r) * DD, xkb, lane);
                float p1 = (r1 < r_end) ? dotrow<WT, 2>(fkw, (gf + r1) * DD, xkb, lane) : 0.f;
                float s0 = wred(p0), s1 = wred(p1);
                if (lane == 0) {
                    float rr0 = fmaxf(s0, 0.f); cst(&P.fk[gf + r], rr0 * rr0);
                    if (r1 < r_end) { float rr1 = fmaxf(s1, 0.f); cst(&P.fk[gf + r1], rr1 * rr1); }
                }
            }
            for (int c = c_beg + wid; c < c_end; c += 8) {
                long rb = ((long)ld + c) * DD;
                float sfr = wred(dotrow<WT, 2>(frw, rb, xrb, lane));
                if (lane == 0) frl[c - c_beg] = 1.f / (1.f + expf(-sfr));
            }
        }
        gbar_arrive(P.bar, lsense); gbar_wait(P.bar, lsense);

        // ================= stage D =================
        if (act && !isHead) {
            for (int c = c_beg + tid; c < c_end; c += NTH)
                cst(&P.sxf[ld + c], xfs[c]);
            #pragma unroll
            for (int j = 0; j < 4; ++j) {   // stage fk -> fklb (bf16, conflict-free)
                int e = (tid << 1) + (j << 10);
                ((unsigned*)fklb)[tid + (j << 9)] =
                    pack_bf2(cld(&P.fk[gf + e]), cld(&P.fk[gf + e + 1]));
            }
            __syncthreads();
            for (int c = c_beg + wid; c < c_end; c += 8) {
                long rb = ((long)ld + c) * FF;
                float fv = wred(dotrow<WT, 8>(fvw, rb, fklb, lane));
                float hh = frl[c - c_beg] * fv;
                if (lane == 0) {
                    int si = ld + c;
                    float v2o = P.v2[si];
                    float vn = v2o + (hh - v2o) * 0.5f;
                    float sp = (vn >= 1.f) ? 1.f : 0.f;
                    P.v2[si] = vn * (1.f - sp);
                    float xn = xl[c] + sp;
                    if (((grp + 1) % 6) == 0) xn *= 0.5f;
                    cst(&P.xg[ld + c], xn);
                }
            }
        }
        gbar_arrive(P.bar, lsense); gbar_wait(P.bar, lsense);
    }
}

// ---------------- VALU head: out[t][v] = sum_k head[v][k]*XbT[k][t] (f32 out) --
__global__ __launch_bounds__(256) void head_simple(const float* __restrict__ head,
                                                   const float* __restrict__ XbT,
                                                   float* __restrict__ out) {
    int wv   = __builtin_amdgcn_readfirstlane(threadIdx.x >> 6);
    int lane = threadIdx.x & 63;
    int v0   = (blockIdx.x * 4 + wv) * 8;
    if (v0 >= VV) return;
    const float* hp[8];
    #pragma unroll
    for (int r = 0; r < 8; ++r) {
        int v = v0 + r; if (v >= VV) v = VV - 1;
        hp[r] = head + (size_t)v * DD;
    }
    float a0[8], a1[8];
    #pragma unroll
    for (int r = 0; r < 8; ++r) { a0[r] = 0.f; a1[r] = 0.f; }
    #pragma unroll 4
    for (int k = 0; k < DD; ++k) {
        float2 x2 = *(const float2*)(XbT + (size_t)k * TTOK + lane * 2);
        #pragma unroll
        for (int r = 0; r < 8; ++r) {
            float hv = hp[r][k];
            a0[r] += hv * x2.x;
            a1[r] += hv * x2.y;
        }
    }
    int t0 = lane * 2, t1 = t0 + 1;
    #pragma unroll
    for (int r = 0; r < 8; ++r) {
        int v = v0 + r;
        if (v < VV) {
            out[(size_t)t0 * VV + v] = a0[r];
            out[(size_t)t1 * VV + v] = a1[r];
        }
    }
}

// ---------------- fp32 -> bf16 conversion ----------------
__global__ void cvt_bf16(const float* __restrict__ s, unsigned short* __restrict__ d, long n) {
    long i = ((long)blockIdx.x * blockDim.x + threadIdx.x) * 4;
    long st = (long)gridDim.x * blockDim.x * 4;
    for (; i < n; i += st) {
        float4 f = *(const float4*)(s + i);
        ushort4 o;
        o.x = f2bf(f.x); o.y = f2bf(f.y); o.z = f2bf(f.z); o.w = f2bf(f.w);
        *(ushort4*)(d + i) = o;
    }
}

// ---------------- host launch ----------------
extern "C" void kernel_launch(void* const* d_in, const int* in_sizes, int n_in,
                              void* d_out, int out_size, void* d_ws, size_t ws_size,
                              hipStream_t stream) {
    (void)in_sizes; (void)n_in; (void)out_size;
    char* base = (char*)d_ws;
    size_t off = 0;
    auto take = [&](size_t bytes) -> void* {
        void* p = base + off;
        off = (off + bytes + 255) & ~(size_t)255;
        return p;
    };
    unsigned* bar = (unsigned*)take(4096);
    float* xg   = (float*)take((size_t)NGRP * DD * 4);
    float* xmid = (float*)take((size_t)NGRP * DD * 4);
    float* rwkv = (float*)take((size_t)NGRP * DD * 4);
    float* fk   = (float*)take((size_t)NGRP * FF * 4);
    float* td   = (float*)take(LL * DD * 4);
    float* aa   = (float*)take(LL * DD * 4);
    float* bb   = (float*)take(LL * DD * 4);
    float* pp   = (float*)take(LL * DD * 4);
    float* sxa  = (float*)take(LL * DD * 4);
    float* sxf  = (float*)take(LL * DD * 4);
    float* v1   = (float*)take(LL * DD * 4);
    float* v2   = (float*)take(LL * DD * 4);
    float* XbT  = (float*)take((size_t)DD * TTOK * 4);
    size_t wDD = (size_t)LL * DD * DD;
    size_t wFD = (size_t)LL * FF * DD;
    unsigned short* kwb  = (unsigned short*)take(wDD * 2);
    unsigned short* vwb  = (unsigned short*)take(wDD * 2);
    unsigned short* rwb  = (unsigned short*)take(wDD * 2);
    unsigned short* owb  = (unsigned short*)take(wDD * 2);
    unsigned short* frwb = (unsigned short*)take(wDD * 2);
    unsigned short* fkwb = (unsigned short*)take(wFD * 2);
    unsigned short* fvwb = (unsigned short*)take(wFD * 2);
    bool usebf = (ws_size >= off);

    hipMemsetAsync(bar, 0, 4096, stream);

    SP P;
    P.tok = (const int*)d_in[0];
    P.emb = (const float*)d_in[1];
    P.pos = (const float*)d_in[2];
    P.l0w = (const float*)d_in[3];  P.l0b = (const float*)d_in[4];
    P.l1w = (const float*)d_in[5];  P.l1b = (const float*)d_in[6];
    P.l2w = (const float*)d_in[7];  P.l2b = (const float*)d_in[8];
    P.tmk = (const float*)d_in[9];  P.tmv = (const float*)d_in[10]; P.tmr = (const float*)d_in[11];
    P.tf  = (const float*)d_in[12]; P.tdr = (const float*)d_in[13];
    P.ftmk = (const float*)d_in[18]; P.ftmr = (const float*)d_in[19];
    P.low = (const float*)d_in[23]; P.lob = (const float*)d_in[24];
    P.xg = xg; P.xmid = xmid; P.rwkv = rwkv; P.fk = fk; P.td = td;
    P.aa = aa; P.bb = bb; P.pp = pp; P.sxa = sxa; P.sxf = sxf; P.v1 = v1; P.v2 = v2;
    P.XbT = XbT; P.bar = bar;

    if (usebf) {
        struct CV { const float* s; unsigned short* d; size_t n; } cv[7] = {
            {(const float*)d_in[14], kwb,  wDD}, {(const float*)d_in[15], vwb,  wDD},
            {(const float*)d_in[16], rwb,  wDD}, {(const float*)d_in[17], owb,  wDD},
            {(const float*)d_in[22], frwb, wDD},
            {(const float*)d_in[20], fkwb, wFD}, {(const float*)d_in[21], fvwb, wFD},
        };
        for (int i = 0; i < 7; ++i)
            cvt_bf16<<<dim3(2048), dim3(256), 0, stream>>>(cv[i].s, cv[i].d, (long)cv[i].n);
        P.kw = kwb; P.vw = vwb; P.rw = rwb; P.ow = owb; P.fkw = fkwb; P.fvw = fvwb; P.frw = frwb;
        spike_wave<unsigned short><<<dim3(NBLK), dim3(NTH), 0, stream>>>(P);
    } else {
        P.kw = d_in[14]; P.vw = d_in[15]; P.rw = d_in[16]; P.ow = d_in[17];
        P.fkw = d_in[20]; P.fvw = d_in[21]; P.frw = d_in[22];
        spike_wave<float><<<dim3(NBLK), dim3(NTH), 0, stream>>>(P);
    }
    int nwave = (VV + 7) / 8;
    int nblk  = (nwave + 3) / 4;
    head_simple<<<dim3(nblk), dim3(256), 0, stream>>>((const float*)d_in[25], XbT,
                                                      (float*)d_out);
}

// Round 7
// 12143.376 us; speedup vs baseline: 24.9614x; 1.1295x over previous
//
#include <hip/hip_runtime.h>
#include <hip/hip_bf16.h>
#include <hip/hip_fp8.h>

// ---------------- constants ----------------
#define LL   12
#define DD   1024
#define FF   4096
#define TTOK 128
#define VV   50257
#define NBLK 512
#define NTH  512
#define NGRP 12
#define GBLK 42                 // blocks per layer group (12*42=504, +8 head)
#define NGB  (NBLK / 32)        // barrier leaf groups = 16
#define NSTEP (TTOK + NGRP)     // 140 wavefront steps
#define WSC  256.0f             // fp8 encode scale
#define XSC  (1.0f / 256.0f)    // folded into x staging

// ---------------- coherent (cross-XCD) access helpers ----------------
__device__ __forceinline__ float cld(const float* p) {
    return __hip_atomic_load((float*)p, __ATOMIC_RELAXED, __HIP_MEMORY_SCOPE_AGENT);
}
__device__ __forceinline__ void cst(float* p, float v) {
    __hip_atomic_store(p, v, __ATOMIC_RELAXED, __HIP_MEMORY_SCOPE_AGENT);
}

// ---------------- small helpers ----------------
__device__ __host__ __forceinline__ unsigned short f2bf(float f) {
    union { float f; unsigned u; } x; x.f = f;
    unsigned r = x.u + 0x7fffu + ((x.u >> 16) & 1u);
    return (unsigned short)(r >> 16);
}

__device__ __forceinline__ unsigned pack_bf2(float a, float b) {
    return (unsigned)f2bf(a) | ((unsigned)f2bf(b) << 16);
}

__device__ __forceinline__ void ld8(const float* p, float* o) {
    float4 a = ((const float4*)p)[0], b = ((const float4*)p)[1];
    o[0]=a.x; o[1]=a.y; o[2]=a.z; o[3]=a.w; o[4]=b.x; o[5]=b.y; o[6]=b.z; o[7]=b.w;
}

__device__ __forceinline__ void bf8unpack(uint4 u, float* o) {
    union { unsigned u; float f; } t;
    t.u = u.x << 16;         o[0] = t.f;
    t.u = u.x & 0xffff0000u; o[1] = t.f;
    t.u = u.y << 16;         o[2] = t.f;
    t.u = u.y & 0xffff0000u; o[3] = t.f;
    t.u = u.z << 16;         o[4] = t.f;
    t.u = u.z & 0xffff0000u; o[5] = t.f;
    t.u = u.w << 16;         o[6] = t.f;
    t.u = u.w & 0xffff0000u; o[7] = t.f;
}

// bf16 LDS chunk read: chunk = 16B = 8 elems
__device__ __forceinline__ void xld8(const unsigned short* x, int chunk, float* o) {
    uint4 u = *reinterpret_cast<const uint4*>(x + (chunk << 3));
    bf8unpack(u, o);
}

// ---------------- fp8 e4m3 decode/encode ----------------
typedef __attribute__((ext_vector_type(2))) float f32x2_t;

__device__ __forceinline__ void fp8x4(unsigned v, float* o) {
#if __has_builtin(__builtin_amdgcn_cvt_pk_f32_fp8)
    f32x2_t a = __builtin_amdgcn_cvt_pk_f32_fp8(v, false);
    f32x2_t b = __builtin_amdgcn_cvt_pk_f32_fp8(v, true);
    o[0] = a[0]; o[1] = a[1]; o[2] = b[0]; o[3] = b[1];
#else
    #pragma unroll
    for (int i = 0; i < 4; ++i) {
        __hip_fp8_e4m3 t; t.__x = (__hip_fp8_storage_t)((v >> (8 * i)) & 0xffu);
        o[i] = (float)t;
    }
#endif
}

__device__ __forceinline__ unsigned enc_fp8x4(float4 f) {
#if __has_builtin(__builtin_amdgcn_cvt_pk_fp8_f32)
    int d = 0;
    d = __builtin_amdgcn_cvt_pk_fp8_f32(f.x, f.y, d, false);
    d = __builtin_amdgcn_cvt_pk_fp8_f32(f.z, f.w, d, true);
    return (unsigned)d;
#else
    __hip_fp8_e4m3 a(f.x), b(f.y), c(f.z), e(f.w);
    return (unsigned)a.__x | ((unsigned)b.__x << 8) |
           ((unsigned)c.__x << 16) | ((unsigned)e.__x << 24);
#endif
}

__device__ __forceinline__ float dot8(const float* w, const float* x) {
    return w[0]*x[0]+w[1]*x[1]+w[2]*x[2]+w[3]*x[3]+w[4]*x[4]+w[5]*x[5]+w[6]*x[6]+w[7]*x[7];
}

__device__ __forceinline__ float dot16u(uint4 w, const float* x) {
    float wf[4], s;
    fp8x4(w.x, wf); s  = wf[0]*x[0] +wf[1]*x[1] +wf[2]*x[2] +wf[3]*x[3];
    fp8x4(w.y, wf); s += wf[0]*x[4] +wf[1]*x[5] +wf[2]*x[6] +wf[3]*x[7];
    fp8x4(w.z, wf); s += wf[0]*x[8] +wf[1]*x[9] +wf[2]*x[10]+wf[3]*x[11];
    fp8x4(w.w, wf); s += wf[0]*x[12]+wf[1]*x[13]+wf[2]*x[14]+wf[3]*x[15];
    return s;
}

__device__ __forceinline__ float wred(float s) {
    #pragma unroll
    for (int o = 32; o; o >>= 1) s += __shfl_xor(s, o, 64);
    return s;
}

// row dot partial. F8: weight bytes pre-swizzled so lane's uint4 = elems
// {m*1024 + 8*lane + j} ∪ {m*1024 + 512 + 8*lane + j}, matching two LDS chunks.
template<bool F8, int SEGS>
__device__ __forceinline__ float rowdot(const void* w, long row,
                                        const unsigned short* xb, int lane) {
    float s = 0.f;
    if constexpr (F8) {
        const unsigned char* p = (const unsigned char*)w + row * (SEGS << 10);
        #pragma unroll
        for (int m = 0; m < SEGS; ++m) {
            uint4 wv = *(const uint4*)(p + (m << 10) + (lane << 4));
            float xf[16];
            xld8(xb, (m << 7) + lane, xf);
            xld8(xb, (m << 7) + 64 + lane, xf + 8);
            s += dot16u(wv, xf);
        }
    } else {
        const float* p = (const float*)w + row * (SEGS << 10);
        #pragma unroll
        for (int m = 0; m < SEGS * 2; ++m) {
            int ch = lane + (m << 6);
            float wf[8], xf[8];
            ld8(p + (ch << 3), wf);
            xld8(xb, ch, xf);
            s += dot8(wf, xf);
        }
    }
    return s;
}

// block stats over xl[1024] (512 threads): mean + rstd
__device__ __forceinline__ void bstats(const float* xl, float* red, float& m, float& rs) {
    int tid = threadIdx.x;
    float a = xl[tid], b = xl[tid + 512];
    float s0 = a + b, s1 = a*a + b*b;
    #pragma unroll
    for (int o = 32; o; o >>= 1) { s0 += __shfl_xor(s0, o, 64); s1 += __shfl_xor(s1, o, 64); }
    if ((tid & 63) == 0) { red[(tid >> 6) * 2] = s0; red[(tid >> 6) * 2 + 1] = s1; }
    __syncthreads();
    float ms = 0.f, qs = 0.f;
    #pragma unroll
    for (int w = 0; w < 8; ++w) { ms += red[w * 2]; qs += red[w * 2 + 1]; }
    ms *= (1.f / 1024.f); qs *= (1.f / 1024.f);
    m = ms; rs = rsqrtf(qs - ms * ms + 1e-5f);
    __syncthreads();
}

// ---------------- grid barrier: fence-free, two-level, sense-reversing -------
__device__ __forceinline__ void gbar_arrive(unsigned* bar, unsigned lsense) {
    __syncthreads();
    if (threadIdx.x == 0) {
        unsigned s = lsense ^ 1u;
        int g = blockIdx.x >> 5;
        unsigned prev = __hip_atomic_fetch_add(&bar[g * 16], 1u,
                            __ATOMIC_RELAXED, __HIP_MEMORY_SCOPE_AGENT);
        if (prev == 31u) {
            unsigned p2 = __hip_atomic_fetch_add(&bar[256], 1u,
                              __ATOMIC_RELAXED, __HIP_MEMORY_SCOPE_AGENT);
            if (p2 == (unsigned)(NGB - 1)) {
                #pragma unroll
                for (int i = 0; i < NGB; ++i)
                    __hip_atomic_store(&bar[i * 16], 0u, __ATOMIC_RELAXED, __HIP_MEMORY_SCOPE_AGENT);
                __hip_atomic_store(&bar[256], 0u, __ATOMIC_RELAXED, __HIP_MEMORY_SCOPE_AGENT);
                asm volatile("s_waitcnt vmcnt(0)" ::: "memory");
                #pragma unroll
                for (int i = 0; i < NGB; ++i)
                    __hip_atomic_store(&bar[288 + i * 16], s, __ATOMIC_RELAXED, __HIP_MEMORY_SCOPE_AGENT);
            }
        }
    }
}

__device__ __forceinline__ void gbar_wait(unsigned* bar, unsigned& lsense) {
    unsigned s = lsense ^ 1u;
    if (threadIdx.x == 0) {
        int g = blockIdx.x >> 5;
        while (__hip_atomic_load(&bar[288 + g * 16], __ATOMIC_RELAXED,
                                 __HIP_MEMORY_SCOPE_AGENT) != s)
            __builtin_amdgcn_s_sleep(2);
    }
    lsense = s;
    __syncthreads();
}

// ---------------- params ----------------
struct SP {
    const int* tok; const float* emb; const float* pos;
    const float *l0w, *l0b, *l1w, *l1b, *l2w, *l2b;
    const float *tmk, *tmv, *tmr, *tf, *tdr;
    const float *ftmk, *ftmr, *low, *lob;
    const void *kw, *vw, *rw, *ow, *fkw, *fvw, *frw;
    float *xg, *xmid, *rwkv, *fk, *td;
    float *aa, *bb, *pp, *sxa, *sxf, *v1, *v2;
    float* XbT;          // [DD][TTOK]
    unsigned* bar;
};

// ---------------- layer-wavefront persistent kernel ----------------
template<bool F8>
__global__ __launch_bounds__(NTH, 4) void spike_wave(SP P) {
    const void* kw  = P.kw;
    const void* vw  = P.vw;
    const void* rw  = P.rw;
    const void* ow  = P.ow;
    const void* fkw = P.fkw;
    const void* fvw = P.fvw;
    const void* frw = P.frw;
    constexpr float XS = F8 ? XSC : 1.0f;

    __shared__ float xl[DD], xas[DD], xfs[DD];
    __shared__ __align__(16) unsigned short xkb[DD], xvb[DD], xrb[DD];
    __shared__ __align__(16) unsigned short fklb[FF];
    __shared__ float red[16];
    __shared__ float frl[32];

    const int tid  = threadIdx.x;
    const int b    = blockIdx.x;
    const int wid  = tid >> 6;
    const int lane = tid & 63;
    const bool isHead = (b >= NGRP * GBLK);
    const int grp = isHead ? NGRP : (b / GBLK);
    const int gi  = isHead ? (b - NGRP * GBLK) : (b % GBLK);
    int c_beg = 0, c_end = 0, r_beg = 0, r_end = 0;
    if (!isHead) {
        c_beg = (gi * DD) / GBLK; c_end = ((gi + 1) * DD) / GBLK;
        r_beg = (gi * FF) / GBLK; r_end = ((gi + 1) * FF) / GBLK;
    }
    const int  ld = (isHead ? 0 : grp) * DD;
    const long gf = (long)(isHead ? 0 : grp) * FF;

    unsigned lsense = 0;

    // ---- init own layer state ----
    if (!isHead) {
        for (int c = c_beg + tid; c < c_end; c += NTH) {
            int si = ld + c;
            P.aa[si] = 0.f; P.bb[si] = 0.f; P.pp[si] = -1e30f;
            P.v1[si] = 0.f; P.v2[si] = 0.f;
            P.td[si] = -expf(P.tdr[si]);
            cst(&P.sxa[si], 0.f); cst(&P.sxf[si], 0.f);
        }
    }
    gbar_arrive(P.bar, lsense); gbar_wait(P.bar, lsense);

    #pragma unroll 1
    for (int s = 0; s < NSTEP; ++s) {
        const int t = s - grp;                 // grp==NGRP -> head token
        const bool act = (t >= 0) && (t < TTOK);

        // ================= stage A =================
        if (act) {
            if (isHead) {
                xl[tid]       = cld(&P.xg[11 * DD + tid]);
                xl[tid + 512] = cld(&P.xg[11 * DD + tid + 512]);
                __syncthreads();
                float m, rs; bstats(xl, red, m, rs);
                for (int cc = (gi << 7) + tid; cc < ((gi + 1) << 7); cc += NTH)
                    P.XbT[(size_t)cc * TTOK + t] = (xl[cc] - m) * rs * P.low[cc] + P.lob[cc];
            } else {
                if (grp == 0) {
                    int tk = P.tok[t];
                    float e0 = P.emb[(size_t)tk * DD + tid]       + P.pos[(size_t)t * DD + tid];
                    float e1 = P.emb[(size_t)tk * DD + tid + 512] + P.pos[(size_t)t * DD + tid + 512];
                    xl[tid] = e0; xl[tid + 512] = e1;
                    __syncthreads();
                    float m, rs; bstats(xl, red, m, rs);
                    xl[tid]       = (e0 - m) * rs * P.l0w[tid]       + P.l0b[tid];
                    xl[tid + 512] = (e1 - m) * rs * P.l0w[tid + 512] + P.l0b[tid + 512];
                    __syncthreads();
                } else {
                    xl[tid]       = cld(&P.xg[(grp - 1) * DD + tid]);
                    xl[tid + 512] = cld(&P.xg[(grp - 1) * DD + tid + 512]);
                    __syncthreads();
                }
                float m1, rs1; bstats(xl, red, m1, rs1);
                {   // LN1 + mixes (thread handles elems 2tid, 2tid+1); XS folded in
                    int i2 = tid << 1;
                    float2 w2 = *(const float2*)&P.l1w[ld + i2];
                    float2 b2 = *(const float2*)&P.l1b[ld + i2];
                    float a0 = (xl[i2]     - m1) * rs1 * w2.x + b2.x;
                    float a1 = (xl[i2 + 1] - m1) * rs1 * w2.y + b2.y;
                    xas[i2] = a0; xas[i2 + 1] = a1;
                    float sx0 = cld(&P.sxa[ld + i2]), sx1 = cld(&P.sxa[ld + i2 + 1]);
                    float2 u2;
                    u2 = *(const float2*)&P.tmk[ld + i2];
                    ((unsigned*)xkb)[tid] = pack_bf2((a0*u2.x + sx0*(1.f-u2.x))*XS, (a1*u2.y + sx1*(1.f-u2.y))*XS);
                    u2 = *(const float2*)&P.tmv[ld + i2];
                    ((unsigned*)xvb)[tid] = pack_bf2((a0*u2.x + sx0*(1.f-u2.x))*XS, (a1*u2.y + sx1*(1.f-u2.y))*XS);
                    u2 = *(const float2*)&P.tmr[ld + i2];
                    ((unsigned*)xrb)[tid] = pack_bf2((a0*u2.x + sx0*(1.f-u2.x))*XS, (a1*u2.y + sx1*(1.f-u2.y))*XS);
                }
                __syncthreads();
                for (int c = c_beg + wid; c < c_end; c += 8) {
                    long rb = (long)ld + c;
                    float pk = rowdot<F8, 1>(kw, rb, xkb, lane);
                    float pv = rowdot<F8, 1>(vw, rb, xvb, lane);
                    float pr = rowdot<F8, 1>(rw, rb, xrb, lane);
                    float sk = wred(pk), sv = wred(pv), sr = wred(pr);
                    if (lane == 0) {
                        int si = ld + c;
                        float aa = P.aa[si], bb = P.bb[si], pp = P.pp[si];
                        float ww = P.tf[si] + sk;
                        float q  = fmaxf(pp, ww);
                        float e1 = expf(pp - q), e2 = expf(ww - q);
                        float an = e1 * aa + e2 * sv, bn = e1 * bb + e2;
                        float ww2 = pp + P.td[si];
                        float q2  = fmaxf(ww2, sk);
                        float e1b = expf(ww2 - q2), e2b = expf(sk - q2);
                        P.aa[si] = e1b * aa + e2b * sv;
                        P.bb[si] = e1b * bb + e2b;
                        P.pp[si] = q2;
                        float sg = 1.f / (1.f + expf(-sr));
                        cst(&P.rwkv[ld + c], sg * (an / bn));
                    }
                }
            }
        }
        gbar_arrive(P.bar, lsense); gbar_wait(P.bar, lsense);

        // ================= stage B =================
        if (act && !isHead) {
            for (int c = c_beg + tid; c < c_end; c += NTH)
                cst(&P.sxa[ld + c], xas[c]);
            {   // stage rwkv -> xvb (bf16, XS folded)
                int i2 = tid << 1;
                ((unsigned*)xvb)[tid] = pack_bf2(cld(&P.rwkv[ld + i2]) * XS,
                                                 cld(&P.rwkv[ld + i2 + 1]) * XS);
            }
            __syncthreads();
            for (int c = c_beg + wid; c < c_end; c += 16) {
                int c1 = c + 8;
                float p0 = rowdot<F8, 1>(ow, (long)ld + c, xvb, lane);
                float p1 = (c1 < c_end) ? rowdot<F8, 1>(ow, (long)ld + c1, xvb, lane) : 0.f;
                float s0 = wred(p0), s1 = wred(p1);
                if (lane == 0) {
                    {
                        int si = ld + c;
                        float v1o = P.v1[si];
                        float vn = v1o + (s0 - v1o) * 0.5f;
                        float sp = (vn >= 1.f) ? 1.f : 0.f;
                        P.v1[si] = vn * (1.f - sp);
                        cst(&P.xmid[ld + c], xl[c] + sp);
                    }
                    if (c1 < c_end) {
                        int si = ld + c1;
                        float v1o = P.v1[si];
                        float vn = v1o + (s1 - v1o) * 0.5f;
                        float sp = (vn >= 1.f) ? 1.f : 0.f;
                        P.v1[si] = vn * (1.f - sp);
                        cst(&P.xmid[ld + c1], xl[c1] + sp);
                    }
                }
            }
        }
        gbar_arrive(P.bar, lsense); gbar_wait(P.bar, lsense);

        // ================= stage C =================
        if (act && !isHead) {
            xl[tid]       = cld(&P.xmid[ld + tid]);
            xl[tid + 512] = cld(&P.xmid[ld + tid + 512]);
            __syncthreads();
            float m2, rs2; bstats(xl, red, m2, rs2);
            {   // LN2 + FFN mixes (XS folded)
                int i2 = tid << 1;
                float2 w2 = *(const float2*)&P.l2w[ld + i2];
                float2 b2 = *(const float2*)&P.l2b[ld + i2];
                float f0 = (xl[i2]     - m2) * rs2 * w2.x + b2.x;
                float f1 = (xl[i2 + 1] - m2) * rs2 * w2.y + b2.y;
                xfs[i2] = f0; xfs[i2 + 1] = f1;
                float sx0 = cld(&P.sxf[ld + i2]), sx1 = cld(&P.sxf[ld + i2 + 1]);
                float2 u2;
                u2 = *(const float2*)&P.ftmk[ld + i2];
                ((unsigned*)xkb)[tid] = pack_bf2((f0*u2.x + sx0*(1.f-u2.x))*XS, (f1*u2.y + sx1*(1.f-u2.y))*XS);
                u2 = *(const float2*)&P.ftmr[ld + i2];
                ((unsigned*)xrb)[tid] = pack_bf2((f0*u2.x + sx0*(1.f-u2.x))*XS, (f1*u2.y + sx1*(1.f-u2.y))*XS);
            }
            __syncthreads();
            // fkw rows: 4-row batch for loads-in-flight
            for (int r = r_beg + wid; r < r_end; r += 32) {
                int r1 = r + 8, r2 = r + 16, r3 = r + 24;
                float p0 = rowdot<F8, 1>(fkw, gf + r, xkb, lane);
                float p1 = (r1 < r_end) ? rowdot<F8, 1>(fkw, gf + r1, xkb, lane) : 0.f;
                float p2 = (r2 < r_end) ? rowdot<F8, 1>(fkw, gf + r2, xkb, lane) : 0.f;
                float p3 = (r3 < r_end) ? rowdot<F8, 1>(fkw, gf + r3, xkb, lane) : 0.f;
                float s0 = wred(p0), s1 = wred(p1), s2 = wred(p2), s3 = wred(p3);
                if (lane == 0) {
                    float rr = fmaxf(s0, 0.f); cst(&P.fk[gf + r], rr * rr);
                    if (r1 < r_end) { rr = fmaxf(s1, 0.f); cst(&P.fk[gf + r1], rr * rr); }
                    if (r2 < r_end) { rr = fmaxf(s2, 0.f); cst(&P.fk[gf + r2], rr * rr); }
                    if (r3 < r_end) { rr = fmaxf(s3, 0.f); cst(&P.fk[gf + r3], rr * rr); }
                }
            }
            for (int c = c_beg + wid; c < c_end; c += 8) {
                float sfr = wred(rowdot<F8, 1>(frw, (long)ld + c, xrb, lane));
                if (lane == 0) frl[c - c_beg] = 1.f / (1.f + expf(-sfr));
            }
        }
        gbar_arrive(P.bar, lsense); gbar_wait(P.bar, lsense);

        // ================= stage D =================
        if (act && !isHead) {
            for (int c = c_beg + tid; c < c_end; c += NTH)
                cst(&P.sxf[ld + c], xfs[c]);
            #pragma unroll
            for (int j = 0; j < 4; ++j) {   // stage fk -> fklb (bf16, XS folded)
                int e = (tid << 1) + (j << 10);
                ((unsigned*)fklb)[tid + (j << 9)] =
                    pack_bf2(cld(&P.fk[gf + e]) * XS, cld(&P.fk[gf + e + 1]) * XS);
            }
            __syncthreads();
            for (int c = c_beg + wid; c < c_end; c += 16) {
                int c1 = c + 8;
                float q0 = rowdot<F8, 4>(fvw, (long)ld + c, fklb, lane);
                float q1 = (c1 < c_end) ? rowdot<F8, 4>(fvw, (long)ld + c1, fklb, lane) : 0.f;
                float f0 = wred(q0), f1 = wred(q1);
                if (lane == 0) {
                    {
                        float hh = frl[c - c_beg] * f0;
                        int si = ld + c;
                        float v2o = P.v2[si];
                        float vn = v2o + (hh - v2o) * 0.5f;
                        float sp = (vn >= 1.f) ? 1.f : 0.f;
                        P.v2[si] = vn * (1.f - sp);
                        float xn = xl[c] + sp;
                        if (((grp + 1) % 6) == 0) xn *= 0.5f;
                        cst(&P.xg[ld + c], xn);
                    }
                    if (c1 < c_end) {
                        float hh = frl[c1 - c_beg] * f1;
                        int si = ld + c1;
                        float v2o = P.v2[si];
                        float vn = v2o + (hh - v2o) * 0.5f;
                        float sp = (vn >= 1.f) ? 1.f : 0.f;
                        P.v2[si] = vn * (1.f - sp);
                        float xn = xl[c1] + sp;
                        if (((grp + 1) % 6) == 0) xn *= 0.5f;
                        cst(&P.xg[ld + c1], xn);
                    }
                }
            }
        }
        gbar_arrive(P.bar, lsense); gbar_wait(P.bar, lsense);
    }
}

// ---------------- VALU head: out[t][v] = sum_k head[v][k]*XbT[k][t] (f32 out) --
__global__ __launch_bounds__(256) void head_simple(const float* __restrict__ head,
                                                   const float* __restrict__ XbT,
                                                   float* __restrict__ out) {
    int wv   = __builtin_amdgcn_readfirstlane(threadIdx.x >> 6);
    int lane = threadIdx.x & 63;
    int v0   = (blockIdx.x * 4 + wv) * 8;
    if (v0 >= VV) return;
    const float* hp[8];
    #pragma unroll
    for (int r = 0; r < 8; ++r) {
        int v = v0 + r; if (v >= VV) v = VV - 1;
        hp[r] = head + (size_t)v * DD;
    }
    float a0[8], a1[8];
    #pragma unroll
    for (int r = 0; r < 8; ++r) { a0[r] = 0.f; a1[r] = 0.f; }
    #pragma unroll 4
    for (int k = 0; k < DD; ++k) {
        float2 x2 = *(const float2*)(XbT + (size_t)k * TTOK + lane * 2);
        #pragma unroll
        for (int r = 0; r < 8; ++r) {
            float hv = hp[r][k];
            a0[r] += hv * x2.x;
            a1[r] += hv * x2.y;
        }
    }
    int t0 = lane * 2, t1 = t0 + 1;
    #pragma unroll
    for (int r = 0; r < 8; ++r) {
        int v = v0 + r;
        if (v < VV) {
            out[(size_t)t0 * VV + v] = a0[r];
            out[(size_t)t1 * VV + v] = a1[r];
        }
    }
}

// ---------------- f32 -> fp8 (scaled ×WSC, swizzled) ----------------
// Output byte p within a 1024-elem segment: u=(p&1023)>>4, half=(p>>3)&1, j=p&7
// encodes source elem  seg*1024 + half*512 + u*8 + j.
__global__ void cvt_fp8(const float* __restrict__ s, unsigned char* __restrict__ d, long n) {
    long p4 = ((long)blockIdx.x * blockDim.x + threadIdx.x) * 4;
    long st = (long)gridDim.x * blockDim.x * 4;
    for (; p4 < n; p4 += st) {
        long seg = p4 >> 10;
        int  q   = (int)(p4 & 1023);
        int  u   = q >> 4, rem = q & 15, half = rem >> 3, j0 = rem & 7;
        long e = (seg << 10) + ((long)half << 9) + (u << 3) + j0;
        float4 f = *(const float4*)(s + e);
        f.x *= WSC; f.y *= WSC; f.z *= WSC; f.w *= WSC;
        *(unsigned*)(d + p4) = enc_fp8x4(f);
    }
}

// ---------------- host launch ----------------
extern "C" void kernel_launch(void* const* d_in, const int* in_sizes, int n_in,
                              void* d_out, int out_size, void* d_ws, size_t ws_size,
                              hipStream_t stream) {
    (void)in_sizes; (void)n_in; (void)out_size;
    char* base = (char*)d_ws;
    size_t off = 0;
    auto take = [&](size_t bytes) -> void* {
        void* p = base + off;
        off = (off + bytes + 255) & ~(size_t)255;
        return p;
    };
    unsigned* bar = (unsigned*)take(4096);
    float* xg   = (float*)take((size_t)NGRP * DD * 4);
    float* xmid = (float*)take((size_t)NGRP * DD * 4);
    float* rwkv = (float*)take((size_t)NGRP * DD * 4);
    float* fk   = (float*)take((size_t)NGRP * FF * 4);
    float* td   = (float*)take(LL * DD * 4);
    float* aa   = (float*)take(LL * DD * 4);
    float* bb   = (float*)take(LL * DD * 4);
    float* pp   = (float*)take(LL * DD * 4);
    float* sxa  = (float*)take(LL * DD * 4);
    float* sxf  = (float*)take(LL * DD * 4);
    float* v1   = (float*)take(LL * DD * 4);
    float* v2   = (float*)take(LL * DD * 4);
    float* XbT  = (float*)take((size_t)DD * TTOK * 4);
    size_t wDD = (size_t)LL * DD * DD;
    size_t wFD = (size_t)LL * FF * DD;
    unsigned char* kwb  = (unsigned char*)take(wDD);
    unsigned char* vwb  = (unsigned char*)take(wDD);
    unsigned char* rwb  = (unsigned char*)take(wDD);
    unsigned char* owb  = (unsigned char*)take(wDD);
    unsigned char* frwb = (unsigned char*)take(wDD);
    unsigned char* fkwb = (unsigned char*)take(wFD);
    unsigned char* fvwb = (unsigned char*)take(wFD);
    bool usef8 = (ws_size >= off);

    hipMemsetAsync(bar, 0, 4096, stream);

    SP P;
    P.tok = (const int*)d_in[0];
    P.emb = (const float*)d_in[1];
    P.pos = (const float*)d_in[2];
    P.l0w = (const float*)d_in[3];  P.l0b = (const float*)d_in[4];
    P.l1w = (const float*)d_in[5];  P.l1b = (const float*)d_in[6];
    P.l2w = (const float*)d_in[7];  P.l2b = (const float*)d_in[8];
    P.tmk = (const float*)d_in[9];  P.tmv = (const float*)d_in[10]; P.tmr = (const float*)d_in[11];
    P.tf  = (const float*)d_in[12]; P.tdr = (const float*)d_in[13];
    P.ftmk = (const float*)d_in[18]; P.ftmr = (const float*)d_in[19];
    P.low = (const float*)d_in[23]; P.lob = (const float*)d_in[24];
    P.xg = xg; P.xmid = xmid; P.rwkv = rwkv; P.fk = fk; P.td = td;
    P.aa = aa; P.bb = bb; P.pp = pp; P.sxa = sxa; P.sxf = sxf; P.v1 = v1; P.v2 = v2;
    P.XbT = XbT; P.bar = bar;

    if (usef8) {
        struct CV { const float* s; unsigned char* d; size_t n; } cv[7] = {
            {(const float*)d_in[14], kwb,  wDD}, {(const float*)d_in[15], vwb,  wDD},
            {(const float*)d_in[16], rwb,  wDD}, {(const float*)d_in[17], owb,  wDD},
            {(const float*)d_in[22], frwb, wDD},
            {(const float*)d_in[20], fkwb, wFD}, {(const float*)d_in[21], fvwb, wFD},
        };
        for (int i = 0; i < 7; ++i)
            cvt_fp8<<<dim3(2048), dim3(256), 0, stream>>>(cv[i].s, cv[i].d, (long)cv[i].n);
        P.kw = kwb; P.vw = vwb; P.rw = rwb; P.ow = owb; P.fkw = fkwb; P.fvw = fvwb; P.frw = frwb;
        spike_wave<true><<<dim3(NBLK), dim3(NTH), 0, stream>>>(P);
    } else {
        P.kw = d_in[14]; P.vw = d_in[15]; P.rw = d_in[16]; P.ow = d_in[17];
        P.fkw = d_in[20]; P.fvw = d_in[21]; P.frw = d_in[22];
        spike_wave<false><<<dim3(NBLK), dim3(NTH), 0, stream>>>(P);
    }
    int nwave = (VV + 7) / 8;
    int nblk  = (nwave + 3) / 4;
    head_simple<<<dim3(nblk), dim3(256), 0, stream>>>((const float*)d_in[25], XbT,
                                                      (float*)d_out);
}

// Round 8
// 11690.556 us; speedup vs baseline: 25.9282x; 1.0387x over previous
//
#include <hip/hip_runtime.h>
#include <hip/hip_bf16.h>
#include <hip/hip_fp8.h>

// ---------------- constants ----------------
#define LL   12
#define DD   1024
#define FF   4096
#define TTOK 128
#define VV   50257
#define NBLK 512
#define NTH  512
#define NGRP 12
#define GBLK 42                 // blocks per layer group (12*42=504, +8 head)
#define NGB  (NBLK / 32)        // barrier leaf groups = 16
#define NSTEP (TTOK + NGRP)     // 140 wavefront steps
#define WSC  256.0f             // fp8 encode scale
#define XSC  (1.0f / 256.0f)    // folded into x staging

// ---------------- coherent (cross-XCD) access helpers ----------------
__device__ __forceinline__ float cld(const float* p) {
    return __hip_atomic_load((float*)p, __ATOMIC_RELAXED, __HIP_MEMORY_SCOPE_AGENT);
}
__device__ __forceinline__ void cst(float* p, float v) {
    __hip_atomic_store(p, v, __ATOMIC_RELAXED, __HIP_MEMORY_SCOPE_AGENT);
}

// ---------------- small helpers ----------------
__device__ __host__ __forceinline__ unsigned short f2bf(float f) {
    union { float f; unsigned u; } x; x.f = f;
    unsigned r = x.u + 0x7fffu + ((x.u >> 16) & 1u);
    return (unsigned short)(r >> 16);
}

__device__ __forceinline__ unsigned pack_bf2(float a, float b) {
    return (unsigned)f2bf(a) | ((unsigned)f2bf(b) << 16);
}

__device__ __forceinline__ void ld8(const float* p, float* o) {
    float4 a = ((const float4*)p)[0], b = ((const float4*)p)[1];
    o[0]=a.x; o[1]=a.y; o[2]=a.z; o[3]=a.w; o[4]=b.x; o[5]=b.y; o[6]=b.z; o[7]=b.w;
}

__device__ __forceinline__ void bf8unpack(uint4 u, float* o) {
    union { unsigned u; float f; } t;
    t.u = u.x << 16;         o[0] = t.f;
    t.u = u.x & 0xffff0000u; o[1] = t.f;
    t.u = u.y << 16;         o[2] = t.f;
    t.u = u.y & 0xffff0000u; o[3] = t.f;
    t.u = u.z << 16;         o[4] = t.f;
    t.u = u.z & 0xffff0000u; o[5] = t.f;
    t.u = u.w << 16;         o[6] = t.f;
    t.u = u.w & 0xffff0000u; o[7] = t.f;
}

// bf16 LDS chunk read: chunk = 16B = 8 elems
__device__ __forceinline__ void xld8(const unsigned short* x, int chunk, float* o) {
    uint4 u = *reinterpret_cast<const uint4*>(x + (chunk << 3));
    bf8unpack(u, o);
}

// ---------------- fp8 e4m3 decode/encode ----------------
typedef __attribute__((ext_vector_type(2))) float f32x2_t;

__device__ __forceinline__ void fp8x4(unsigned v, float* o) {
#if __has_builtin(__builtin_amdgcn_cvt_pk_f32_fp8)
    f32x2_t a = __builtin_amdgcn_cvt_pk_f32_fp8(v, false);
    f32x2_t b = __builtin_amdgcn_cvt_pk_f32_fp8(v, true);
    o[0] = a[0]; o[1] = a[1]; o[2] = b[0]; o[3] = b[1];
#else
    #pragma unroll
    for (int i = 0; i < 4; ++i) {
        __hip_fp8_e4m3 t; t.__x = (__hip_fp8_storage_t)((v >> (8 * i)) & 0xffu);
        o[i] = (float)t;
    }
#endif
}

__device__ __forceinline__ unsigned enc_fp8x4(float4 f) {
#if __has_builtin(__builtin_amdgcn_cvt_pk_fp8_f32)
    int d = 0;
    d = __builtin_amdgcn_cvt_pk_fp8_f32(f.x, f.y, d, false);
    d = __builtin_amdgcn_cvt_pk_fp8_f32(f.z, f.w, d, true);
    return (unsigned)d;
#else
    __hip_fp8_e4m3 a(f.x), b(f.y), c(f.z), e(f.w);
    return (unsigned)a.__x | ((unsigned)b.__x << 8) |
           ((unsigned)c.__x << 16) | ((unsigned)e.__x << 24);
#endif
}

__device__ __forceinline__ float dot8(const float* w, const float* x) {
    return w[0]*x[0]+w[1]*x[1]+w[2]*x[2]+w[3]*x[3]+w[4]*x[4]+w[5]*x[5]+w[6]*x[6]+w[7]*x[7];
}

// fp8 uint4 (16 weights) dot 16 resident f32 x values
__device__ __forceinline__ float dot16u(uint4 w, const float* x) {
    float wf[4], s;
    fp8x4(w.x, wf); s  = wf[0]*x[0] +wf[1]*x[1] +wf[2]*x[2] +wf[3]*x[3];
    fp8x4(w.y, wf); s += wf[0]*x[4] +wf[1]*x[5] +wf[2]*x[6] +wf[3]*x[7];
    fp8x4(w.z, wf); s += wf[0]*x[8] +wf[1]*x[9] +wf[2]*x[10]+wf[3]*x[11];
    fp8x4(w.w, wf); s += wf[0]*x[12]+wf[1]*x[13]+wf[2]*x[14]+wf[3]*x[15];
    return s;
}

__device__ __forceinline__ float wred(float s) {
    #pragma unroll
    for (int o = 32; o; o >>= 1) s += __shfl_xor(s, o, 64);
    return s;
}

// f32 fallback row dot (old path)
template<int SEGS>
__device__ __forceinline__ float rowdot_f32(const void* w, long row,
                                            const unsigned short* xb, int lane) {
    float s = 0.f;
    const float* p = (const float*)w + row * (SEGS << 10);
    #pragma unroll
    for (int m = 0; m < SEGS * 2; ++m) {
        int ch = lane + (m << 6);
        float wf[8], xf[8];
        ld8(p + (ch << 3), wf);
        xld8(xb, ch, xf);
        s += dot8(wf, xf);
    }
    return s;
}

// block stats over xl[1024] (512 threads): mean + rstd
__device__ __forceinline__ void bstats(const float* xl, float* red, float& m, float& rs) {
    int tid = threadIdx.x;
    float a = xl[tid], b = xl[tid + 512];
    float s0 = a + b, s1 = a*a + b*b;
    #pragma unroll
    for (int o = 32; o; o >>= 1) { s0 += __shfl_xor(s0, o, 64); s1 += __shfl_xor(s1, o, 64); }
    if ((tid & 63) == 0) { red[(tid >> 6) * 2] = s0; red[(tid >> 6) * 2 + 1] = s1; }
    __syncthreads();
    float ms = 0.f, qs = 0.f;
    #pragma unroll
    for (int w = 0; w < 8; ++w) { ms += red[w * 2]; qs += red[w * 2 + 1]; }
    ms *= (1.f / 1024.f); qs *= (1.f / 1024.f);
    m = ms; rs = rsqrtf(qs - ms * ms + 1e-5f);
    __syncthreads();
}

// ---------------- grid barrier: fence-free, two-level, sense-reversing -------
__device__ __forceinline__ void gbar_arrive(unsigned* bar, unsigned lsense) {
    __syncthreads();
    if (threadIdx.x == 0) {
        unsigned s = lsense ^ 1u;
        int g = blockIdx.x >> 5;
        unsigned prev = __hip_atomic_fetch_add(&bar[g * 16], 1u,
                            __ATOMIC_RELAXED, __HIP_MEMORY_SCOPE_AGENT);
        if (prev == 31u) {
            unsigned p2 = __hip_atomic_fetch_add(&bar[256], 1u,
                              __ATOMIC_RELAXED, __HIP_MEMORY_SCOPE_AGENT);
            if (p2 == (unsigned)(NGB - 1)) {
                #pragma unroll
                for (int i = 0; i < NGB; ++i)
                    __hip_atomic_store(&bar[i * 16], 0u, __ATOMIC_RELAXED, __HIP_MEMORY_SCOPE_AGENT);
                __hip_atomic_store(&bar[256], 0u, __ATOMIC_RELAXED, __HIP_MEMORY_SCOPE_AGENT);
                asm volatile("s_waitcnt vmcnt(0)" ::: "memory");
                #pragma unroll
                for (int i = 0; i < NGB; ++i)
                    __hip_atomic_store(&bar[288 + i * 16], s, __ATOMIC_RELAXED, __HIP_MEMORY_SCOPE_AGENT);
            }
        }
    }
}

__device__ __forceinline__ void gbar_wait(unsigned* bar, unsigned& lsense) {
    unsigned s = lsense ^ 1u;
    if (threadIdx.x == 0) {
        int g = blockIdx.x >> 5;
        while (__hip_atomic_load(&bar[288 + g * 16], __ATOMIC_RELAXED,
                                 __HIP_MEMORY_SCOPE_AGENT) != s)
            __builtin_amdgcn_s_sleep(2);
    }
    lsense = s;
    __syncthreads();
}

// ---------------- params ----------------
struct SP {
    const int* tok; const float* emb; const float* pos;
    const float *l0w, *l0b, *l1w, *l1b, *l2w, *l2b;
    const float *tmk, *tmv, *tmr, *tf, *tdr;
    const float *ftmk, *ftmr, *low, *lob;
    const void *kw, *vw, *rw, *ow, *fkw, *fvw, *frw;
    float *xg, *xmid, *rwkv, *fk, *td;
    float *aa, *bb, *pp, *sxa, *sxf, *v1, *v2;
    float* XbT;          // [DD][TTOK]
    unsigned* bar;
};

// ---------------- layer-wavefront persistent kernel ----------------
template<bool F8>
__global__ __launch_bounds__(NTH, 4) void spike_wave(SP P) {
    const void* kw  = P.kw;
    const void* vw  = P.vw;
    const void* rw  = P.rw;
    const void* ow  = P.ow;
    const void* fkw = P.fkw;
    const void* fvw = P.fvw;
    const void* frw = P.frw;
    constexpr float XS = F8 ? XSC : 1.0f;

    __shared__ float xl[DD], xas[DD], xfs[DD];
    __shared__ __align__(16) unsigned short xkb[DD], xvb[DD], xrb[DD];
    __shared__ __align__(16) unsigned short fklb[FF];
    __shared__ float red[16];
    __shared__ float frl[32];

    const int tid  = threadIdx.x;
    const int b    = blockIdx.x;
    const int wid  = tid >> 6;
    const int lane = tid & 63;
    const bool isHead = (b >= NGRP * GBLK);
    const int grp = isHead ? NGRP : (b / GBLK);
    const int gi  = isHead ? (b - NGRP * GBLK) : (b % GBLK);
    int c_beg = 0, c_end = 0, r_beg = 0, r_end = 0;
    if (!isHead) {
        c_beg = (gi * DD) / GBLK; c_end = ((gi + 1) * DD) / GBLK;
        r_beg = (gi * FF) / GBLK; r_end = ((gi + 1) * FF) / GBLK;
    }
    const int  ld = (isHead ? 0 : grp) * DD;
    const long gf = (long)(isHead ? 0 : grp) * FF;

    // WKV + LIF update lambdas (lane 0 only)
    auto dowkv = [&](int c, float sk, float sv, float sr) {
        int si = ld + c;
        float aa = P.aa[si], bb = P.bb[si], pp = P.pp[si];
        float ww = P.tf[si] + sk;
        float q  = fmaxf(pp, ww);
        float e1 = expf(pp - q), e2 = expf(ww - q);
        float an = e1 * aa + e2 * sv, bn = e1 * bb + e2;
        float ww2 = pp + P.td[si];
        float q2  = fmaxf(ww2, sk);
        float e1b = expf(ww2 - q2), e2b = expf(sk - q2);
        P.aa[si] = e1b * aa + e2b * sv;
        P.bb[si] = e1b * bb + e2b;
        P.pp[si] = q2;
        float sg = 1.f / (1.f + expf(-sr));
        cst(&P.rwkv[ld + c], sg * (an / bn));
    };
    auto lif1 = [&](int c, float so) {
        int si = ld + c;
        float v1o = P.v1[si];
        float vn = v1o + (so - v1o) * 0.5f;
        float sp = (vn >= 1.f) ? 1.f : 0.f;
        P.v1[si] = vn * (1.f - sp);
        cst(&P.xmid[ld + c], xl[c] + sp);
    };
    auto lif2 = [&](int c, float fv) {
        float hh = frl[c - c_beg] * fv;
        int si = ld + c;
        float v2o = P.v2[si];
        float vn = v2o + (hh - v2o) * 0.5f;
        float sp = (vn >= 1.f) ? 1.f : 0.f;
        P.v2[si] = vn * (1.f - sp);
        float xn = xl[c] + sp;
        if (((grp + 1) % 6) == 0) xn *= 0.5f;
        cst(&P.xg[ld + c], xn);
    };

    unsigned lsense = 0;

    // ---- init own layer state ----
    if (!isHead) {
        for (int c = c_beg + tid; c < c_end; c += NTH) {
            int si = ld + c;
            P.aa[si] = 0.f; P.bb[si] = 0.f; P.pp[si] = -1e30f;
            P.v1[si] = 0.f; P.v2[si] = 0.f;
            P.td[si] = -expf(P.tdr[si]);
            cst(&P.sxa[si], 0.f); cst(&P.sxf[si], 0.f);
        }
    }
    gbar_arrive(P.bar, lsense); gbar_wait(P.bar, lsense);

    #pragma unroll 1
    for (int s = 0; s < NSTEP; ++s) {
        const int t = s - grp;                 // grp==NGRP -> head token
        const bool act = (t >= 0) && (t < TTOK);

        // ================= stage A =================
        if (act) {
            if (isHead) {
                xl[tid]       = cld(&P.xg[11 * DD + tid]);
                xl[tid + 512] = cld(&P.xg[11 * DD + tid + 512]);
                __syncthreads();
                float m, rs; bstats(xl, red, m, rs);
                for (int cc = (gi << 7) + tid; cc < ((gi + 1) << 7); cc += NTH)
                    P.XbT[(size_t)cc * TTOK + t] = (xl[cc] - m) * rs * P.low[cc] + P.lob[cc];
            } else {
                if (grp == 0) {
                    int tk = P.tok[t];
                    float e0 = P.emb[(size_t)tk * DD + tid]       + P.pos[(size_t)t * DD + tid];
                    float e1 = P.emb[(size_t)tk * DD + tid + 512] + P.pos[(size_t)t * DD + tid + 512];
                    xl[tid] = e0; xl[tid + 512] = e1;
                    __syncthreads();
                    float m, rs; bstats(xl, red, m, rs);
                    xl[tid]       = (e0 - m) * rs * P.l0w[tid]       + P.l0b[tid];
                    xl[tid + 512] = (e1 - m) * rs * P.l0w[tid + 512] + P.l0b[tid + 512];
                    __syncthreads();
                } else {
                    xl[tid]       = cld(&P.xg[(grp - 1) * DD + tid]);
                    xl[tid + 512] = cld(&P.xg[(grp - 1) * DD + tid + 512]);
                    __syncthreads();
                }
                float m1, rs1; bstats(xl, red, m1, rs1);
                {   // LN1 + mixes (thread handles elems 2tid, 2tid+1); XS folded in
                    int i2 = tid << 1;
                    float2 w2 = *(const float2*)&P.l1w[ld + i2];
                    float2 b2 = *(const float2*)&P.l1b[ld + i2];
                    float a0 = (xl[i2]     - m1) * rs1 * w2.x + b2.x;
                    float a1 = (xl[i2 + 1] - m1) * rs1 * w2.y + b2.y;
                    xas[i2] = a0; xas[i2 + 1] = a1;
                    float sx0 = cld(&P.sxa[ld + i2]), sx1 = cld(&P.sxa[ld + i2 + 1]);
                    float2 u2;
                    u2 = *(const float2*)&P.tmk[ld + i2];
                    ((unsigned*)xkb)[tid] = pack_bf2((a0*u2.x + sx0*(1.f-u2.x))*XS, (a1*u2.y + sx1*(1.f-u2.y))*XS);
                    u2 = *(const float2*)&P.tmv[ld + i2];
                    ((unsigned*)xvb)[tid] = pack_bf2((a0*u2.x + sx0*(1.f-u2.x))*XS, (a1*u2.y + sx1*(1.f-u2.y))*XS);
                    u2 = *(const float2*)&P.tmr[ld + i2];
                    ((unsigned*)xrb)[tid] = pack_bf2((a0*u2.x + sx0*(1.f-u2.x))*XS, (a1*u2.y + sx1*(1.f-u2.y))*XS);
                }
                __syncthreads();
                if constexpr (F8) {
                    float xk16[16], xv16[16], xr16[16];
                    xld8(xkb, lane, xk16); xld8(xkb, lane + 64, xk16 + 8);
                    xld8(xvb, lane, xv16); xld8(xvb, lane + 64, xv16 + 8);
                    xld8(xrb, lane, xr16); xld8(xrb, lane + 64, xr16 + 8);
                    for (int c = c_beg + wid; c < c_end; c += 16) {
                        int c1 = c + 8; bool h1 = (c1 < c_end);
                        long o0 = (((long)ld + c) << 10) + (lane << 4);
                        long o1 = (((long)ld + (h1 ? c1 : c)) << 10) + (lane << 4);
                        uint4 ka = *(const uint4*)((const unsigned char*)kw + o0);
                        uint4 kb = *(const uint4*)((const unsigned char*)kw + o1);
                        uint4 va = *(const uint4*)((const unsigned char*)vw + o0);
                        uint4 vb = *(const uint4*)((const unsigned char*)vw + o1);
                        uint4 ra = *(const uint4*)((const unsigned char*)rw + o0);
                        uint4 rb = *(const uint4*)((const unsigned char*)rw + o1);
                        float sk0 = wred(dot16u(ka, xk16));
                        float sv0 = wred(dot16u(va, xv16));
                        float sr0 = wred(dot16u(ra, xr16));
                        float sk1 = wred(dot16u(kb, xk16));
                        float sv1 = wred(dot16u(vb, xv16));
                        float sr1 = wred(dot16u(rb, xr16));
                        if (lane == 0) {
                            dowkv(c, sk0, sv0, sr0);
                            if (h1) dowkv(c1, sk1, sv1, sr1);
                        }
                    }
                } else {
                    for (int c = c_beg + wid; c < c_end; c += 8) {
                        float sk = wred(rowdot_f32<1>(kw, (long)ld + c, xkb, lane));
                        float sv = wred(rowdot_f32<1>(vw, (long)ld + c, xvb, lane));
                        float sr = wred(rowdot_f32<1>(rw, (long)ld + c, xrb, lane));
                        if (lane == 0) dowkv(c, sk, sv, sr);
                    }
                }
            }
        }
        gbar_arrive(P.bar, lsense); gbar_wait(P.bar, lsense);

        // ================= stage B =================
        if (act && !isHead) {
            for (int c = c_beg + tid; c < c_end; c += NTH)
                cst(&P.sxa[ld + c], xas[c]);
            {   // stage rwkv -> xvb (bf16, XS folded)
                int i2 = tid << 1;
                ((unsigned*)xvb)[tid] = pack_bf2(cld(&P.rwkv[ld + i2]) * XS,
                                                 cld(&P.rwkv[ld + i2 + 1]) * XS);
            }
            __syncthreads();
            if constexpr (F8) {
                float xv16[16];
                xld8(xvb, lane, xv16); xld8(xvb, lane + 64, xv16 + 8);
                for (int c0 = c_beg + wid; c0 < c_end; c0 += 32) {
                    uint4 wv[4]; int n = 0;
                    #pragma unroll
                    for (int k = 0; k < 4; ++k) {
                        int c = c0 + (k << 3);
                        if (c < c_end) {
                            wv[k] = *(const uint4*)((const unsigned char*)ow +
                                        ((((long)ld + c) << 10) + (lane << 4)));
                            n = k + 1;
                        }
                    }
                    float sr[4];
                    #pragma unroll
                    for (int k = 0; k < 4; ++k)
                        sr[k] = (k < n) ? wred(dot16u(wv[k], xv16)) : 0.f;
                    if (lane == 0) {
                        #pragma unroll
                        for (int k = 0; k < 4; ++k) {
                            int c = c0 + (k << 3);
                            if (c < c_end) lif1(c, sr[k]);
                        }
                    }
                }
            } else {
                for (int c = c_beg + wid; c < c_end; c += 8) {
                    float so = wred(rowdot_f32<1>(ow, (long)ld + c, xvb, lane));
                    if (lane == 0) lif1(c, so);
                }
            }
        }
        gbar_arrive(P.bar, lsense); gbar_wait(P.bar, lsense);

        // ================= stage C =================
        if (act && !isHead) {
            xl[tid]       = cld(&P.xmid[ld + tid]);
            xl[tid + 512] = cld(&P.xmid[ld + tid + 512]);
            __syncthreads();
            float m2, rs2; bstats(xl, red, m2, rs2);
            {   // LN2 + FFN mixes (XS folded)
                int i2 = tid << 1;
                float2 w2 = *(const float2*)&P.l2w[ld + i2];
                float2 b2 = *(const float2*)&P.l2b[ld + i2];
                float f0 = (xl[i2]     - m2) * rs2 * w2.x + b2.x;
                float f1 = (xl[i2 + 1] - m2) * rs2 * w2.y + b2.y;
                xfs[i2] = f0; xfs[i2 + 1] = f1;
                float sx0 = cld(&P.sxf[ld + i2]), sx1 = cld(&P.sxf[ld + i2 + 1]);
                float2 u2;
                u2 = *(const float2*)&P.ftmk[ld + i2];
                ((unsigned*)xkb)[tid] = pack_bf2((f0*u2.x + sx0*(1.f-u2.x))*XS, (f1*u2.y + sx1*(1.f-u2.y))*XS);
                u2 = *(const float2*)&P.ftmr[ld + i2];
                ((unsigned*)xrb)[tid] = pack_bf2((f0*u2.x + sx0*(1.f-u2.x))*XS, (f1*u2.y + sx1*(1.f-u2.y))*XS);
            }
            __syncthreads();
            if constexpr (F8) {
                float xk16[16], xr16[16];
                xld8(xkb, lane, xk16); xld8(xkb, lane + 64, xk16 + 8);
                xld8(xrb, lane, xr16); xld8(xrb, lane + 64, xr16 + 8);
                // fkw rows: 6-row batches with resident x
                int r = r_beg + wid;
                while (r < r_end) {
                    uint4 wv[6]; int n = 0;
                    #pragma unroll
                    for (int k = 0; k < 6; ++k) {
                        int ri = r + (k << 3);
                        if (ri < r_end) {
                            wv[k] = *(const uint4*)((const unsigned char*)fkw +
                                        (((gf + ri) << 10) + (lane << 4)));
                            n = k + 1;
                        }
                    }
                    #pragma unroll
                    for (int k = 0; k < 6; ++k) {
                        if (k < n) {
                            float sv = wred(dot16u(wv[k], xk16));
                            int ri = r + (k << 3);
                            if (lane == 0) { float tt = fmaxf(sv, 0.f); cst(&P.fk[gf + ri], tt * tt); }
                        }
                    }
                    r += 48;
                }
                // frw: 4-channel batch
                for (int c0 = c_beg + wid; c0 < c_end; c0 += 32) {
                    uint4 wv[4]; int n = 0;
                    #pragma unroll
                    for (int k = 0; k < 4; ++k) {
                        int c = c0 + (k << 3);
                        if (c < c_end) {
                            wv[k] = *(const uint4*)((const unsigned char*)frw +
                                        ((((long)ld + c) << 10) + (lane << 4)));
                            n = k + 1;
                        }
                    }
                    float sr[4];
                    #pragma unroll
                    for (int k = 0; k < 4; ++k)
                        sr[k] = (k < n) ? wred(dot16u(wv[k], xr16)) : 0.f;
                    if (lane == 0) {
                        #pragma unroll
                        for (int k = 0; k < 4; ++k) {
                            int c = c0 + (k << 3);
                            if (c < c_end) frl[c - c_beg] = 1.f / (1.f + expf(-sr[k]));
                        }
                    }
                }
            } else {
                for (int r = r_beg + wid; r < r_end; r += 8) {
                    float sv = wred(rowdot_f32<1>(fkw, gf + r, xkb, lane));
                    if (lane == 0) { float tt = fmaxf(sv, 0.f); cst(&P.fk[gf + r], tt * tt); }
                }
                for (int c = c_beg + wid; c < c_end; c += 8) {
                    float sfr = wred(rowdot_f32<1>(frw, (long)ld + c, xrb, lane));
                    if (lane == 0) frl[c - c_beg] = 1.f / (1.f + expf(-sfr));
                }
            }
        }
        gbar_arrive(P.bar, lsense); gbar_wait(P.bar, lsense);

        // ================= stage D =================
        if (act && !isHead) {
            for (int c = c_beg + tid; c < c_end; c += NTH)
                cst(&P.sxf[ld + c], xfs[c]);
            #pragma unroll
            for (int j = 0; j < 4; ++j) {   // stage fk -> fklb (bf16, XS folded)
                int e = (tid << 1) + (j << 10);
                ((unsigned*)fklb)[tid + (j << 9)] =
                    pack_bf2(cld(&P.fk[gf + e]) * XS, cld(&P.fk[gf + e + 1]) * XS);
            }
            __syncthreads();
            if constexpr (F8) {
                for (int c = c_beg + wid; c < c_end; c += 16) {
                    int c1 = c + 8; bool h1 = (c1 < c_end);
                    uint4 w0[4], w1[4];
                    #pragma unroll
                    for (int m = 0; m < 4; ++m) {
                        long o0 = (((long)ld + c) << 12) + (m << 10) + (lane << 4);
                        long o1 = (((long)ld + (h1 ? c1 : c)) << 12) + (m << 10) + (lane << 4);
                        w0[m] = *(const uint4*)((const unsigned char*)fvw + o0);
                        w1[m] = *(const uint4*)((const unsigned char*)fvw + o1);
                    }
                    float a0 = 0.f, a1 = 0.f;
                    #pragma unroll
                    for (int m = 0; m < 4; ++m) {
                        float xf[16];
                        xld8(fklb, (m << 7) + lane, xf);
                        xld8(fklb, (m << 7) + 64 + lane, xf + 8);
                        a0 += dot16u(w0[m], xf);
                        a1 += dot16u(w1[m], xf);
                    }
                    float f0 = wred(a0), f1 = wred(a1);
                    if (lane == 0) {
                        lif2(c, f0);
                        if (h1) lif2(c1, f1);
                    }
                }
            } else {
                for (int c = c_beg + wid; c < c_end; c += 8) {
                    float fv = wred(rowdot_f32<4>(fvw, (long)ld + c, fklb, lane));
                    if (lane == 0) lif2(c, fv);
                }
            }
        }
        gbar_arrive(P.bar, lsense); gbar_wait(P.bar, lsense);
    }
}

// ---------------- VALU head: out[t][v] = sum_k head[v][k]*XbT[k][t] (f32 out) --
__global__ __launch_bounds__(256) void head_simple(const float* __restrict__ head,
                                                   const float* __restrict__ XbT,
                                                   float* __restrict__ out) {
    int wv   = __builtin_amdgcn_readfirstlane(threadIdx.x >> 6);
    int lane = threadIdx.x & 63;
    int v0   = (blockIdx.x * 4 + wv) * 8;
    if (v0 >= VV) return;
    const float* hp[8];
    #pragma unroll
    for (int r = 0; r < 8; ++r) {
        int v = v0 + r; if (v >= VV) v = VV - 1;
        hp[r] = head + (size_t)v * DD;
    }
    float a0[8], a1[8];
    #pragma unroll
    for (int r = 0; r < 8; ++r) { a0[r] = 0.f; a1[r] = 0.f; }
    #pragma unroll 4
    for (int k = 0; k < DD; ++k) {
        float2 x2 = *(const float2*)(XbT + (size_t)k * TTOK + lane * 2);
        #pragma unroll
        for (int r = 0; r < 8; ++r) {
            float hv = hp[r][k];
            a0[r] += hv * x2.x;
            a1[r] += hv * x2.y;
        }
    }
    int t0 = lane * 2, t1 = t0 + 1;
    #pragma unroll
    for (int r = 0; r < 8; ++r) {
        int v = v0 + r;
        if (v < VV) {
            out[(size_t)t0 * VV + v] = a0[r];
            out[(size_t)t1 * VV + v] = a1[r];
        }
    }
}

// ---------------- f32 -> fp8 (scaled ×WSC, swizzled) ----------------
__global__ void cvt_fp8(const float* __restrict__ s, unsigned char* __restrict__ d, long n) {
    long p4 = ((long)blockIdx.x * blockDim.x + threadIdx.x) * 4;
    long st = (long)gridDim.x * blockDim.x * 4;
    for (; p4 < n; p4 += st) {
        long seg = p4 >> 10;
        int  q   = (int)(p4 & 1023);
        int  u   = q >> 4, rem = q & 15, half = rem >> 3, j0 = rem & 7;
        long e = (seg << 10) + ((long)half << 9) + (u << 3) + j0;
        float4 f = *(const float4*)(s + e);
        f.x *= WSC; f.y *= WSC; f.z *= WSC; f.w *= WSC;
        *(unsigned*)(d + p4) = enc_fp8x4(f);
    }
}

// ---------------- host launch ----------------
extern "C" void kernel_launch(void* const* d_in, const int* in_sizes, int n_in,
                              void* d_out, int out_size, void* d_ws, size_t ws_size,
                              hipStream_t stream) {
    (void)in_sizes; (void)n_in; (void)out_size;
    char* base = (char*)d_ws;
    size_t off = 0;
    auto take = [&](size_t bytes) -> void* {
        void* p = base + off;
        off = (off + bytes + 255) & ~(size_t)255;
        return p;
    };
    unsigned* bar = (unsigned*)take(4096);
    float* xg   = (float*)take((size_t)NGRP * DD * 4);
    float* xmid = (float*)take((size_t)NGRP * DD * 4);
    float* rwkv = (float*)take((size_t)NGRP * DD * 4);
    float* fk   = (float*)take((size_t)NGRP * FF * 4);
    float* td   = (float*)take(LL * DD * 4);
    float* aa   = (float*)take(LL * DD * 4);
    float* bb   = (float*)take(LL * DD * 4);
    float* pp   = (float*)take(LL * DD * 4);
    float* sxa  = (float*)take(LL * DD * 4);
    float* sxf  = (float*)take(LL * DD * 4);
    float* v1   = (float*)take(LL * DD * 4);
    float* v2   = (float*)take(LL * DD * 4);
    float* XbT  = (float*)take((size_t)DD * TTOK * 4);
    size_t wDD = (size_t)LL * DD * DD;
    size_t wFD = (size_t)LL * FF * DD;
    unsigned char* kwb  = (unsigned char*)take(wDD);
    unsigned char* vwb  = (unsigned char*)take(wDD);
    unsigned char* rwb  = (unsigned char*)take(wDD);
    unsigned char* owb  = (unsigned char*)take(wDD);
    unsigned char* frwb = (unsigned char*)take(wDD);
    unsigned char* fkwb = (unsigned char*)take(wFD);
    unsigned char* fvwb = (unsigned char*)take(wFD);
    bool usef8 = (ws_size >= off);

    hipMemsetAsync(bar, 0, 4096, stream);

    SP P;
    P.tok = (const int*)d_in[0];
    P.emb = (const float*)d_in[1];
    P.pos = (const float*)d_in[2];
    P.l0w = (const float*)d_in[3];  P.l0b = (const float*)d_in[4];
    P.l1w = (const float*)d_in[5];  P.l1b = (const float*)d_in[6];
    P.l2w = (const float*)d_in[7];  P.l2b = (const float*)d_in[8];
    P.tmk = (const float*)d_in[9];  P.tmv = (const float*)d_in[10]; P.tmr = (const float*)d_in[11];
    P.tf  = (const float*)d_in[12]; P.tdr = (const float*)d_in[13];
    P.ftmk = (const float*)d_in[18]; P.ftmr = (const float*)d_in[19];
    P.low = (const float*)d_in[23]; P.lob = (const float*)d_in[24];
    P.xg = xg; P.xmid = xmid; P.rwkv = rwkv; P.fk = fk; P.td = td;
    P.aa = aa; P.bb = bb; P.pp = pp; P.sxa = sxa; P.sxf = sxf; P.v1 = v1; P.v2 = v2;
    P.XbT = XbT; P.bar = bar;

    if (usef8) {
        struct CV { const float* s; unsigned char* d; size_t n; } cv[7] = {
            {(const float*)d_in[14], kwb,  wDD}, {(const float*)d_in[15], vwb,  wDD},
            {(const float*)d_in[16], rwb,  wDD}, {(const float*)d_in[17], owb,  wDD},
            {(const float*)d_in[22], frwb, wDD},
            {(const float*)d_in[20], fkwb, wFD}, {(const float*)d_in[21], fvwb, wFD},
        };
        for (int i = 0; i < 7; ++i)
            cvt_fp8<<<dim3(2048), dim3(256), 0, stream>>>(cv[i].s, cv[i].d, (long)cv[i].n);
        P.kw = kwb; P.vw = vwb; P.rw = rwb; P.ow = owb; P.fkw = fkwb; P.fvw = fvwb; P.frw = frwb;
        spike_wave<true><<<dim3(NBLK), dim3(NTH), 0, stream>>>(P);
    } else {
        P.kw = d_in[14]; P.vw = d_in[15]; P.rw = d_in[16]; P.ow = d_in[17];
        P.fkw = d_in[20]; P.fvw = d_in[21]; P.frw = d_in[22];
        spike_wave<false><<<dim3(NBLK), dim3(NTH), 0, stream>>>(P);
    }
    int nwave = (VV + 7) / 8;
    int nblk  = (nwave + 3) / 4;
    head_simple<<<dim3(nblk), dim3(256), 0, stream>>>((const float*)d_in[25], XbT,
                                                      (float*)d_out);
}

// Round 9
// 7476.021 us; speedup vs baseline: 40.5450x; 1.5637x over previous
//
#include <hip/hip_runtime.h>
#include <hip/hip_bf16.h>
#include <hip/hip_fp8.h>

// ---------------- constants ----------------
#define LL   12
#define DD   1024
#define FF   4096
#define TTOK 128
#define VV   50257
#define NBLK 512
#define NTH  512
#define NGRP 12
#define GBLK 42                 // blocks per layer group (12*42=504, +8 head)
#define NHEAD (NBLK - NGRP * GBLK)
#define NSTEP (TTOK + NGRP + 1) // head finishes token 127 at s = 139
#define WSC  256.0f             // fp8 encode scale
#define XSC  (1.0f / 256.0f)    // folded into x staging

// ---------------- coherent (cross-XCD) access helpers ----------------
__device__ __forceinline__ float cld(const float* p) {
    return __hip_atomic_load((float*)p, __ATOMIC_RELAXED, __HIP_MEMORY_SCOPE_AGENT);
}
__device__ __forceinline__ void cst(float* p, float v) {
    __hip_atomic_store(p, v, __ATOMIC_RELAXED, __HIP_MEMORY_SCOPE_AGENT);
}

// ---------------- small helpers ----------------
__device__ __host__ __forceinline__ unsigned short f2bf(float f) {
    union { float f; unsigned u; } x; x.f = f;
    unsigned r = x.u + 0x7fffu + ((x.u >> 16) & 1u);
    return (unsigned short)(r >> 16);
}

__device__ __forceinline__ unsigned pack_bf2(float a, float b) {
    return (unsigned)f2bf(a) | ((unsigned)f2bf(b) << 16);
}

__device__ __forceinline__ void ld8(const float* p, float* o) {
    float4 a = ((const float4*)p)[0], b = ((const float4*)p)[1];
    o[0]=a.x; o[1]=a.y; o[2]=a.z; o[3]=a.w; o[4]=b.x; o[5]=b.y; o[6]=b.z; o[7]=b.w;
}

__device__ __forceinline__ void bf8unpack(uint4 u, float* o) {
    union { unsigned u; float f; } t;
    t.u = u.x << 16;         o[0] = t.f;
    t.u = u.x & 0xffff0000u; o[1] = t.f;
    t.u = u.y << 16;         o[2] = t.f;
    t.u = u.y & 0xffff0000u; o[3] = t.f;
    t.u = u.z << 16;         o[4] = t.f;
    t.u = u.z & 0xffff0000u; o[5] = t.f;
    t.u = u.w << 16;         o[6] = t.f;
    t.u = u.w & 0xffff0000u; o[7] = t.f;
}

// bf16 LDS chunk read: chunk = 16B = 8 elems
__device__ __forceinline__ void xld8(const unsigned short* x, int chunk, float* o) {
    uint4 u = *reinterpret_cast<const uint4*>(x + (chunk << 3));
    bf8unpack(u, o);
}

// ---------------- fp8 e4m3 decode/encode ----------------
typedef __attribute__((ext_vector_type(2))) float f32x2_t;

__device__ __forceinline__ void fp8x4(unsigned v, float* o) {
#if __has_builtin(__builtin_amdgcn_cvt_pk_f32_fp8)
    f32x2_t a = __builtin_amdgcn_cvt_pk_f32_fp8(v, false);
    f32x2_t b = __builtin_amdgcn_cvt_pk_f32_fp8(v, true);
    o[0] = a[0]; o[1] = a[1]; o[2] = b[0]; o[3] = b[1];
#else
    #pragma unroll
    for (int i = 0; i < 4; ++i) {
        __hip_fp8_e4m3 t; t.__x = (__hip_fp8_storage_t)((v >> (8 * i)) & 0xffu);
        o[i] = (float)t;
    }
#endif
}

__device__ __forceinline__ unsigned enc_fp8x4(float4 f) {
#if __has_builtin(__builtin_amdgcn_cvt_pk_fp8_f32)
    int d = 0;
    d = __builtin_amdgcn_cvt_pk_fp8_f32(f.x, f.y, d, false);
    d = __builtin_amdgcn_cvt_pk_fp8_f32(f.z, f.w, d, true);
    return (unsigned)d;
#else
    __hip_fp8_e4m3 a(f.x), b(f.y), c(f.z), e(f.w);
    return (unsigned)a.__x | ((unsigned)b.__x << 8) |
           ((unsigned)c.__x << 16) | ((unsigned)e.__x << 24);
#endif
}

__device__ __forceinline__ float dot8(const float* w, const float* x) {
    return w[0]*x[0]+w[1]*x[1]+w[2]*x[2]+w[3]*x[3]+w[4]*x[4]+w[5]*x[5]+w[6]*x[6]+w[7]*x[7];
}

// fp8 uint4 (16 weights) dot 16 resident f32 x values
__device__ __forceinline__ float dot16u(uint4 w, const float* x) {
    float wf[4], s;
    fp8x4(w.x, wf); s  = wf[0]*x[0] +wf[1]*x[1] +wf[2]*x[2] +wf[3]*x[3];
    fp8x4(w.y, wf); s += wf[0]*x[4] +wf[1]*x[5] +wf[2]*x[6] +wf[3]*x[7];
    fp8x4(w.z, wf); s += wf[0]*x[8] +wf[1]*x[9] +wf[2]*x[10]+wf[3]*x[11];
    fp8x4(w.w, wf); s += wf[0]*x[12]+wf[1]*x[13]+wf[2]*x[14]+wf[3]*x[15];
    return s;
}

__device__ __forceinline__ float wred(float s) {
    #pragma unroll
    for (int o = 32; o; o >>= 1) s += __shfl_xor(s, o, 64);
    return s;
}

// f32 fallback row dot
template<int SEGS>
__device__ __forceinline__ float rowdot_f32(const void* w, long row,
                                            const unsigned short* xb, int lane) {
    float s = 0.f;
    const float* p = (const float*)w + row * (SEGS << 10);
    #pragma unroll
    for (int m = 0; m < SEGS * 2; ++m) {
        int ch = lane + (m << 6);
        float wf[8], xf[8];
        ld8(p + (ch << 3), wf);
        xld8(xb, ch, xf);
        s += dot8(wf, xf);
    }
    return s;
}

// block stats over xl[1024] (512 threads): mean + rstd
__device__ __forceinline__ void bstats(const float* xl, float* red, float& m, float& rs) {
    int tid = threadIdx.x;
    float a = xl[tid], b = xl[tid + 512];
    float s0 = a + b, s1 = a*a + b*b;
    #pragma unroll
    for (int o = 32; o; o >>= 1) { s0 += __shfl_xor(s0, o, 64); s1 += __shfl_xor(s1, o, 64); }
    if ((tid & 63) == 0) { red[(tid >> 6) * 2] = s0; red[(tid >> 6) * 2 + 1] = s1; }
    __syncthreads();
    float ms = 0.f, qs = 0.f;
    #pragma unroll
    for (int w = 0; w < 8; ++w) { ms += red[w * 2]; qs += red[w * 2 + 1]; }
    ms *= (1.f / 1024.f); qs *= (1.f / 1024.f);
    m = ms; rs = rsqrtf(qs - ms * ms + 1e-5f);
    __syncthreads();
}

// ---------------- group barrier (flat counter, sense-reversing) --------------
// per-group slot: counter at bar[grp*64], sense at bar[grp*64+32] (256B apart)
__device__ __forceinline__ void grpbar(unsigned* bar, int grp, unsigned n, unsigned& sen) {
    __syncthreads();     // drains each wave's vmem (sc1 stores reach coherence pt)
    if (threadIdx.x == 0) {
        unsigned s = sen ^ 1u;
        unsigned* cnt = &bar[grp * 64];
        unsigned* sns = &bar[grp * 64 + 32];
        unsigned prev = __hip_atomic_fetch_add(cnt, 1u, __ATOMIC_RELAXED, __HIP_MEMORY_SCOPE_AGENT);
        if (prev == n - 1u) {
            __hip_atomic_store(cnt, 0u, __ATOMIC_RELAXED, __HIP_MEMORY_SCOPE_AGENT);
            asm volatile("s_waitcnt vmcnt(0)" ::: "memory");  // reset lands before flip
            __hip_atomic_store(sns, s, __ATOMIC_RELAXED, __HIP_MEMORY_SCOPE_AGENT);
        } else {
            while (__hip_atomic_load(sns, __ATOMIC_RELAXED, __HIP_MEMORY_SCOPE_AGENT) != s)
                __builtin_amdgcn_s_sleep(1);
        }
    }
    sen ^= 1u;
    __syncthreads();
}

// ---------------- neighbor progress flags ----------------
__device__ __forceinline__ void fpub(unsigned* f, unsigned v) {
    __hip_atomic_store(f, v, __ATOMIC_RELAXED, __HIP_MEMORY_SCOPE_AGENT);
}
__device__ __forceinline__ void fwait(unsigned* f, unsigned v) {
    while (__hip_atomic_load(f, __ATOMIC_RELAXED, __HIP_MEMORY_SCOPE_AGENT) < v)
        __builtin_amdgcn_s_sleep(1);
}

// ---------------- params ----------------
struct SP {
    const int* tok; const float* emb; const float* pos;
    const float *l0w, *l0b, *l1w, *l1b, *l2w, *l2b;
    const float *tmk, *tmv, *tmr, *tf, *tdr;
    const float *ftmk, *ftmr, *low, *lob;
    const void *kw, *vw, *rw, *ow, *fkw, *fvw, *frw;
    float *xg, *xmid, *rwkv, *fk, *td;     // xg: [2][NGRP][DD] double-buffered
    float *aa, *bb, *pp, *sxa, *sxf, *v1, *v2;
    float* XbT;          // [DD][TTOK]
    unsigned* bar;       // [grp*64] counters/senses; +1024 done[]; +2048 rda[]
};

// ---------------- layer-wavefront persistent kernel (flag-decoupled) --------
// groups 0..11 = layers (42 blocks); group 12 = head (8 blocks).
// step s: group l works token t = s - l. Intra-step: 4 group barriers.
// Cross-group: done[l] (xg[l] step-s data ready) / rda[l] (xg[l-1] read done).
template<bool F8>
__global__ __launch_bounds__(NTH, 4) void spike_wave(SP P) {
    const void* kw  = P.kw;
    const void* vw  = P.vw;
    const void* rw  = P.rw;
    const void* ow  = P.ow;
    const void* fkw = P.fkw;
    const void* fvw = P.fvw;
    const void* frw = P.frw;
    constexpr float XS = F8 ? XSC : 1.0f;

    __shared__ float xl[DD], xas[DD], xfs[DD];
    __shared__ __align__(16) unsigned short xkb[DD], xvb[DD], xrb[DD];
    __shared__ __align__(16) unsigned short fklb[FF];
    __shared__ float red[16];
    __shared__ float frl[32];

    const int tid  = threadIdx.x;
    const int b    = blockIdx.x;
    const int wid  = tid >> 6;
    const int lane = tid & 63;
    const bool isHead = (b >= NGRP * GBLK);
    const int grp = isHead ? NGRP : (b / GBLK);
    const int gi  = isHead ? (b - NGRP * GBLK) : (b % GBLK);
    const unsigned gn = isHead ? (unsigned)NHEAD : (unsigned)GBLK;
    int c_beg = 0, c_end = 0, r_beg = 0, r_end = 0;
    if (!isHead) {
        c_beg = (gi * DD) / GBLK; c_end = ((gi + 1) * DD) / GBLK;
        r_beg = (gi * FF) / GBLK; r_end = ((gi + 1) * FF) / GBLK;
    }
    const int  ld = (isHead ? 0 : grp) * DD;
    const long gf = (long)(isHead ? 0 : grp) * FF;

    unsigned* done = P.bar + 1024;
    unsigned* rda  = P.bar + 2048;

    float* xgw = nullptr;        // write target this step (set per step)

    auto dowkv = [&](int c, float sk, float sv, float sr) {
        int si = ld + c;
        float aa = P.aa[si], bb = P.bb[si], pp = P.pp[si];
        float ww = P.tf[si] + sk;
        float q  = fmaxf(pp, ww);
        float e1 = expf(pp - q), e2 = expf(ww - q);
        float an = e1 * aa + e2 * sv, bn = e1 * bb + e2;
        float ww2 = pp + P.td[si];
        float q2  = fmaxf(ww2, sk);
        float e1b = expf(ww2 - q2), e2b = expf(sk - q2);
        P.aa[si] = e1b * aa + e2b * sv;
        P.bb[si] = e1b * bb + e2b;
        P.pp[si] = q2;
        float sg = 1.f / (1.f + expf(-sr));
        cst(&P.rwkv[ld + c], sg * (an / bn));
    };
    auto lif1 = [&](int c, float so) {
        int si = ld + c;
        float v1o = P.v1[si];
        float vn = v1o + (so - v1o) * 0.5f;
        float sp = (vn >= 1.f) ? 1.f : 0.f;
        P.v1[si] = vn * (1.f - sp);
        cst(&P.xmid[ld + c], xl[c] + sp);
    };
    auto lif2 = [&](int c, float fv) {
        float hh = frl[c - c_beg] * fv;
        int si = ld + c;
        float v2o = P.v2[si];
        float vn = v2o + (hh - v2o) * 0.5f;
        float sp = (vn >= 1.f) ? 1.f : 0.f;
        P.v2[si] = vn * (1.f - sp);
        float xn = xl[c] + sp;
        if (((grp + 1) % 6) == 0) xn *= 0.5f;
        cst(&xgw[c], xn);
    };

    unsigned sen = 0;

    // ---- init own layer state ----
    if (!isHead) {
        for (int c = c_beg + tid; c < c_end; c += NTH) {
            int si = ld + c;
            P.aa[si] = 0.f; P.bb[si] = 0.f; P.pp[si] = -1e30f;
            P.v1[si] = 0.f; P.v2[si] = 0.f;
            P.td[si] = -expf(P.tdr[si]);
            cst(&P.sxa[si], 0.f); cst(&P.sxf[si], 0.f);
        }
    }
    grpbar(P.bar, grp, gn, sen);   // init visible within group

    #pragma unroll 1
    for (int s = 0; s < NSTEP; ++s) {
        const int t = s - grp;
        const bool act = (t >= 0) && (t < TTOK);
        const unsigned wbuf = (unsigned)s & 1u, rbuf = wbuf ^ 1u;
        xgw = P.xg + ((size_t)wbuf * NGRP + (isHead ? 0 : grp)) * DD;
        const float* xgr = P.xg + ((size_t)rbuf * NGRP + (grp > 0 ? grp - 1 : 0)) * DD;

        // ================= stage A =================
        if (act) {
            if (isHead) {
                if (tid == 0) fwait(&done[NGRP - 1], (unsigned)s);
                __syncthreads();
                xl[tid]       = cld(&xgr[tid]);
                xl[tid + 512] = cld(&xgr[tid + 512]);
                __syncthreads();
                float m, rs; bstats(xl, red, m, rs);
                for (int cc = (gi << 7) + tid; cc < ((gi + 1) << 7); cc += NTH)
                    P.XbT[(size_t)cc * TTOK + t] = (xl[cc] - m) * rs * P.low[cc] + P.lob[cc];
            } else {
                if (grp == 0) {
                    int tk = P.tok[t];
                    float e0 = P.emb[(size_t)tk * DD + tid]       + P.pos[(size_t)t * DD + tid];
                    float e1 = P.emb[(size_t)tk * DD + tid + 512] + P.pos[(size_t)t * DD + tid + 512];
                    xl[tid] = e0; xl[tid + 512] = e1;
                    __syncthreads();
                    float m, rs; bstats(xl, red, m, rs);
                    xl[tid]       = (e0 - m) * rs * P.l0w[tid]       + P.l0b[tid];
                    xl[tid + 512] = (e1 - m) * rs * P.l0w[tid + 512] + P.l0b[tid + 512];
                    __syncthreads();
                } else {
                    if (tid == 0) fwait(&done[grp - 1], (unsigned)s);
                    __syncthreads();
                    xl[tid]       = cld(&xgr[tid]);
                    xl[tid + 512] = cld(&xgr[tid + 512]);
                    __syncthreads();
                }
                float m1, rs1; bstats(xl, red, m1, rs1);
                {   // LN1 + mixes; XS folded in
                    int i2 = tid << 1;
                    float2 w2 = *(const float2*)&P.l1w[ld + i2];
                    float2 b2 = *(const float2*)&P.l1b[ld + i2];
                    float a0 = (xl[i2]     - m1) * rs1 * w2.x + b2.x;
                    float a1 = (xl[i2 + 1] - m1) * rs1 * w2.y + b2.y;
                    xas[i2] = a0; xas[i2 + 1] = a1;
                    float sx0 = cld(&P.sxa[ld + i2]), sx1 = cld(&P.sxa[ld + i2 + 1]);
                    float2 u2;
                    u2 = *(const float2*)&P.tmk[ld + i2];
                    ((unsigned*)xkb)[tid] = pack_bf2((a0*u2.x + sx0*(1.f-u2.x))*XS, (a1*u2.y + sx1*(1.f-u2.y))*XS);
                    u2 = *(const float2*)&P.tmv[ld + i2];
                    ((unsigned*)xvb)[tid] = pack_bf2((a0*u2.x + sx0*(1.f-u2.x))*XS, (a1*u2.y + sx1*(1.f-u2.y))*XS);
                    u2 = *(const float2*)&P.tmr[ld + i2];
                    ((unsigned*)xrb)[tid] = pack_bf2((a0*u2.x + sx0*(1.f-u2.x))*XS, (a1*u2.y + sx1*(1.f-u2.y))*XS);
                }
                __syncthreads();
                if constexpr (F8) {
                    float xk16[16], xv16[16], xr16[16];
                    xld8(xkb, lane, xk16); xld8(xkb, lane + 64, xk16 + 8);
                    xld8(xvb, lane, xv16); xld8(xvb, lane + 64, xv16 + 8);
                    xld8(xrb, lane, xr16); xld8(xrb, lane + 64, xr16 + 8);
                    for (int c0 = c_beg + wid; c0 < c_end; c0 += 24) {
                        // 3-channel × 3-mat batch: 9 loads in flight
                        uint4 wk[3], wv2[3], wr2[3];
                        #pragma unroll
                        for (int k = 0; k < 3; ++k) {
                            int c = c0 + (k << 3);
                            long o = (((long)ld + (c < c_end ? c : c0)) << 10) + (lane << 4);
                            wk[k]  = *(const uint4*)((const unsigned char*)kw + o);
                            wv2[k] = *(const uint4*)((const unsigned char*)vw + o);
                            wr2[k] = *(const uint4*)((const unsigned char*)rw + o);
                        }
                        float sk[3], sv[3], sr[3];
                        #pragma unroll
                        for (int k = 0; k < 3; ++k) {
                            sk[k] = wred(dot16u(wk[k],  xk16));
                            sv[k] = wred(dot16u(wv2[k], xv16));
                            sr[k] = wred(dot16u(wr2[k], xr16));
                        }
                        if (lane == 0) {
                            #pragma unroll
                            for (int k = 0; k < 3; ++k) {
                                int c = c0 + (k << 3);
                                if (c < c_end) dowkv(c, sk[k], sv[k], sr[k]);
                            }
                        }
                    }
                } else {
                    for (int c = c_beg + wid; c < c_end; c += 8) {
                        float sk = wred(rowdot_f32<1>(kw, (long)ld + c, xkb, lane));
                        float sv = wred(rowdot_f32<1>(vw, (long)ld + c, xvb, lane));
                        float sr = wred(rowdot_f32<1>(rw, (long)ld + c, xrb, lane));
                        if (lane == 0) dowkv(c, sk, sv, sr);
                    }
                }
            }
        }
        grpbar(P.bar, grp, gn, sen);                       // bar1: A done
        if (gi == 0 && tid == 0) fpub(&rda[grp], (unsigned)(s + 1));

        // ================= stage B =================
        if (act && !isHead) {
            for (int c = c_beg + tid; c < c_end; c += NTH)
                cst(&P.sxa[ld + c], xas[c]);
            {
                int i2 = tid << 1;
                float ra = cld(&P.rwkv[ld + i2]), rb2 = cld(&P.rwkv[ld + i2 + 1]);
                ((unsigned*)xvb)[tid] = pack_bf2(ra * XS, rb2 * XS);
            }
            __syncthreads();
            if constexpr (F8) {
                float xv16[16];
                xld8(xvb, lane, xv16); xld8(xvb, lane + 64, xv16 + 8);
                for (int c0 = c_beg + wid; c0 < c_end; c0 += 32) {
                    uint4 wv2[4];
                    #pragma unroll
                    for (int k = 0; k < 4; ++k) {
                        int c = c0 + (k << 3);
                        wv2[k] = *(const uint4*)((const unsigned char*)ow +
                                    ((((long)ld + (c < c_end ? c : c0)) << 10) + (lane << 4)));
                    }
                    float sr[4];
                    #pragma unroll
                    for (int k = 0; k < 4; ++k) sr[k] = wred(dot16u(wv2[k], xv16));
                    if (lane == 0) {
                        #pragma unroll
                        for (int k = 0; k < 4; ++k) {
                            int c = c0 + (k << 3);
                            if (c < c_end) lif1(c, sr[k]);
                        }
                    }
                }
            } else {
                for (int c = c_beg + wid; c < c_end; c += 8) {
                    float so = wred(rowdot_f32<1>(ow, (long)ld + c, xvb, lane));
                    if (lane == 0) lif1(c, so);
                }
            }
        }
        grpbar(P.bar, grp, gn, sen);                       // bar2: B done

        // ================= stage C =================
        if (act && !isHead) {
            xl[tid]       = cld(&P.xmid[ld + tid]);
            xl[tid + 512] = cld(&P.xmid[ld + tid + 512]);
            __syncthreads();
            float m2, rs2; bstats(xl, red, m2, rs2);
            {
                int i2 = tid << 1;
                float2 w2 = *(const float2*)&P.l2w[ld + i2];
                float2 b2 = *(const float2*)&P.l2b[ld + i2];
                float f0 = (xl[i2]     - m2) * rs2 * w2.x + b2.x;
                float f1 = (xl[i2 + 1] - m2) * rs2 * w2.y + b2.y;
                xfs[i2] = f0; xfs[i2 + 1] = f1;
                float sx0 = cld(&P.sxf[ld + i2]), sx1 = cld(&P.sxf[ld + i2 + 1]);
                float2 u2;
                u2 = *(const float2*)&P.ftmk[ld + i2];
                ((unsigned*)xkb)[tid] = pack_bf2((f0*u2.x + sx0*(1.f-u2.x))*XS, (f1*u2.y + sx1*(1.f-u2.y))*XS);
                u2 = *(const float2*)&P.ftmr[ld + i2];
                ((unsigned*)xrb)[tid] = pack_bf2((f0*u2.x + sx0*(1.f-u2.x))*XS, (f1*u2.y + sx1*(1.f-u2.y))*XS);
            }
            __syncthreads();
            if constexpr (F8) {
                float xk16[16], xr16[16];
                xld8(xkb, lane, xk16); xld8(xkb, lane + 64, xk16 + 8);
                xld8(xrb, lane, xr16); xld8(xrb, lane + 64, xr16 + 8);
                int r = r_beg + wid;
                while (r < r_end) {
                    uint4 wv2[6];
                    #pragma unroll
                    for (int k = 0; k < 6; ++k) {
                        int ri = r + (k << 3);
                        wv2[k] = *(const uint4*)((const unsigned char*)fkw +
                                    (((gf + (ri < r_end ? ri : r)) << 10) + (lane << 4)));
                    }
                    #pragma unroll
                    for (int k = 0; k < 6; ++k) {
                        int ri = r + (k << 3);
                        if (ri < r_end) {
                            float sv = wred(dot16u(wv2[k], xk16));
                            if (lane == 0) { float tt = fmaxf(sv, 0.f); cst(&P.fk[gf + ri], tt * tt); }
                        }
                    }
                    r += 48;
                }
                for (int c0 = c_beg + wid; c0 < c_end; c0 += 32) {
                    uint4 wv2[4];
                    #pragma unroll
                    for (int k = 0; k < 4; ++k) {
                        int c = c0 + (k << 3);
                        wv2[k] = *(const uint4*)((const unsigned char*)frw +
                                    ((((long)ld + (c < c_end ? c : c0)) << 10) + (lane << 4)));
                    }
                    float sr[4];
                    #pragma unroll
                    for (int k = 0; k < 4; ++k) sr[k] = wred(dot16u(wv2[k], xr16));
                    if (lane == 0) {
                        #pragma unroll
                        for (int k = 0; k < 4; ++k) {
                            int c = c0 + (k << 3);
                            if (c < c_end) frl[c - c_beg] = 1.f / (1.f + expf(-sr[k]));
                        }
                    }
                }
            } else {
                for (int r = r_beg + wid; r < r_end; r += 8) {
                    float sv = wred(rowdot_f32<1>(fkw, gf + r, xkb, lane));
                    if (lane == 0) { float tt = fmaxf(sv, 0.f); cst(&P.fk[gf + r], tt * tt); }
                }
                for (int c = c_beg + wid; c < c_end; c += 8) {
                    float sfr = wred(rowdot_f32<1>(frw, (long)ld + c, xrb, lane));
                    if (lane == 0) frl[c - c_beg] = 1.f / (1.f + expf(-sfr));
                }
            }
        }
        grpbar(P.bar, grp, gn, sen);                       // bar3: C done

        // ================= stage D =================
        if (act && !isHead) {
            // anti-dependency: consumer (grp+1) must have read xg[wbuf][grp]'s
            // previous content (its step s-1 stage A) before we overwrite.
            if (tid == 0 && s > 0) fwait(&rda[grp + 1], (unsigned)s);
            __syncthreads();
            for (int c = c_beg + tid; c < c_end; c += NTH)
                cst(&P.sxf[ld + c], xfs[c]);
            {   // stage fk -> fklb: issue all 8 sc1 loads, then pack
                float la[4], lb[4];
                #pragma unroll
                for (int j = 0; j < 4; ++j) {
                    int e = (tid << 1) + (j << 10);
                    la[j] = cld(&P.fk[gf + e]);
                    lb[j] = cld(&P.fk[gf + e + 1]);
                }
                #pragma unroll
                for (int j = 0; j < 4; ++j)
                    ((unsigned*)fklb)[tid + (j << 9)] = pack_bf2(la[j] * XS, lb[j] * XS);
            }
            __syncthreads();
            if constexpr (F8) {
                for (int c = c_beg + wid; c < c_end; c += 16) {
                    int c1 = c + 8; bool h1 = (c1 < c_end);
                    uint4 w0[4], w1[4];
                    #pragma unroll
                    for (int m = 0; m < 4; ++m) {
                        long o0 = (((long)ld + c) << 12) + (m << 10) + (lane << 4);
                        long o1 = (((long)ld + (h1 ? c1 : c)) << 12) + (m << 10) + (lane << 4);
                        w0[m] = *(const uint4*)((const unsigned char*)fvw + o0);
                        w1[m] = *(const uint4*)((const unsigned char*)fvw + o1);
                    }
                    float a0 = 0.f, a1 = 0.f;
                    #pragma unroll
                    for (int m = 0; m < 4; ++m) {
                        float xf[16];
                        xld8(fklb, (m << 7) + lane, xf);
                        xld8(fklb, (m << 7) + 64 + lane, xf + 8);
                        a0 += dot16u(w0[m], xf);
                        a1 += dot16u(w1[m], xf);
                    }
                    float f0 = wred(a0), f1 = wred(a1);
                    if (lane == 0) {
                        lif2(c, f0);
                        if (h1) lif2(c1, f1);
                    }
                }
            } else {
                for (int c = c_beg + wid; c < c_end; c += 8) {
                    float fv = wred(rowdot_f32<4>(fvw, (long)ld + c, fklb, lane));
                    if (lane == 0) lif2(c, fv);
                }
            }
        }
        grpbar(P.bar, grp, gn, sen);                       // bar4: D done (xg drained)
        if (gi == 0 && tid == 0) fpub(&done[grp], (unsigned)(s + 1));
    }
}

// ---------------- VALU head: out[t][v] = sum_k head[v][k]*XbT[k][t] (f32 out) --
__global__ __launch_bounds__(256) void head_simple(const float* __restrict__ head,
                                                   const float* __restrict__ XbT,
                                                   float* __restrict__ out) {
    int wv   = __builtin_amdgcn_readfirstlane(threadIdx.x >> 6);
    int lane = threadIdx.x & 63;
    int v0   = (blockIdx.x * 4 + wv) * 8;
    if (v0 >= VV) return;
    const float* hp[8];
    #pragma unroll
    for (int r = 0; r < 8; ++r) {
        int v = v0 + r; if (v >= VV) v = VV - 1;
        hp[r] = head + (size_t)v * DD;
    }
    float a0[8], a1[8];
    #pragma unroll
    for (int r = 0; r < 8; ++r) { a0[r] = 0.f; a1[r] = 0.f; }
    #pragma unroll 4
    for (int k = 0; k < DD; ++k) {
        float2 x2 = *(const float2*)(XbT + (size_t)k * TTOK + lane * 2);
        #pragma unroll
        for (int r = 0; r < 8; ++r) {
            float hv = hp[r][k];
            a0[r] += hv * x2.x;
            a1[r] += hv * x2.y;
        }
    }
    int t0 = lane * 2, t1 = t0 + 1;
    #pragma unroll
    for (int r = 0; r < 8; ++r) {
        int v = v0 + r;
        if (v < VV) {
            out[(size_t)t0 * VV + v] = a0[r];
            out[(size_t)t1 * VV + v] = a1[r];
        }
    }
}

// ---------------- f32 -> fp8 (scaled ×WSC, swizzled) ----------------
__global__ void cvt_fp8(const float* __restrict__ s, unsigned char* __restrict__ d, long n) {
    long p4 = ((long)blockIdx.x * blockDim.x + threadIdx.x) * 4;
    long st = (long)gridDim.x * blockDim.x * 4;
    for (; p4 < n; p4 += st) {
        long seg = p4 >> 10;
        int  q   = (int)(p4 & 1023);
        int  u   = q >> 4, rem = q & 15, half = rem >> 3, j0 = rem & 7;
        long e = (seg << 10) + ((long)half << 9) + (u << 3) + j0;
        float4 f = *(const float4*)(s + e);
        f.x *= WSC; f.y *= WSC; f.z *= WSC; f.w *= WSC;
        *(unsigned*)(d + p4) = enc_fp8x4(f);
    }
}

// ---------------- host launch ----------------
extern "C" void kernel_launch(void* const* d_in, const int* in_sizes, int n_in,
                              void* d_out, int out_size, void* d_ws, size_t ws_size,
                              hipStream_t stream) {
    (void)in_sizes; (void)n_in; (void)out_size;
    char* base = (char*)d_ws;
    size_t off = 0;
    auto take = [&](size_t bytes) -> void* {
        void* p = base + off;
        off = (off + bytes + 255) & ~(size_t)255;
        return p;
    };
    unsigned* bar = (unsigned*)take(16384);
    float* xg   = (float*)take((size_t)2 * NGRP * DD * 4);   // double-buffered
    float* xmid = (float*)take((size_t)NGRP * DD * 4);
    float* rwkv = (float*)take((size_t)NGRP * DD * 4);
    float* fk   = (float*)take((size_t)NGRP * FF * 4);
    float* td   = (float*)take(LL * DD * 4);
    float* aa   = (float*)take(LL * DD * 4);
    float* bb   = (float*)take(LL * DD * 4);
    float* pp   = (float*)take(LL * DD * 4);
    float* sxa  = (float*)take(LL * DD * 4);
    float* sxf  = (float*)take(LL * DD * 4);
    float* v1   = (float*)take(LL * DD * 4);
    float* v2   = (float*)take(LL * DD * 4);
    float* XbT  = (float*)take((size_t)DD * TTOK * 4);
    size_t wDD = (size_t)LL * DD * DD;
    size_t wFD = (size_t)LL * FF * DD;
    unsigned char* kwb  = (unsigned char*)take(wDD);
    unsigned char* vwb  = (unsigned char*)take(wDD);
    unsigned char* rwb  = (unsigned char*)take(wDD);
    unsigned char* owb  = (unsigned char*)take(wDD);
    unsigned char* frwb = (unsigned char*)take(wDD);
    unsigned char* fkwb = (unsigned char*)take(wFD);
    unsigned char* fvwb = (unsigned char*)take(wFD);
    bool usef8 = (ws_size >= off);

    hipMemsetAsync(bar, 0, 16384, stream);

    SP P;
    P.tok = (const int*)d_in[0];
    P.emb = (const float*)d_in[1];
    P.pos = (const float*)d_in[2];
    P.l0w = (const float*)d_in[3];  P.l0b = (const float*)d_in[4];
    P.l1w = (const float*)d_in[5];  P.l1b = (const float*)d_in[6];
    P.l2w = (const float*)d_in[7];  P.l2b = (const float*)d_in[8];
    P.tmk = (const float*)d_in[9];  P.tmv = (const float*)d_in[10]; P.tmr = (const float*)d_in[11];
    P.tf  = (const float*)d_in[12]; P.tdr = (const float*)d_in[13];
    P.ftmk = (const float*)d_in[18]; P.ftmr = (const float*)d_in[19];
    P.low = (const float*)d_in[23]; P.lob = (const float*)d_in[24];
    P.xg = xg; P.xmid = xmid; P.rwkv = rwkv; P.fk = fk; P.td = td;
    P.aa = aa; P.bb = bb; P.pp = pp; P.sxa = sxa; P.sxf = sxf; P.v1 = v1; P.v2 = v2;
    P.XbT = XbT; P.bar = bar;

    if (usef8) {
        struct CV { const float* s; unsigned char* d; size_t n; } cv[7] = {
            {(const float*)d_in[14], kwb,  wDD}, {(const float*)d_in[15], vwb,  wDD},
            {(const float*)d_in[16], rwb,  wDD}, {(const float*)d_in[17], owb,  wDD},
            {(const float*)d_in[22], frwb, wDD},
            {(const float*)d_in[20], fkwb, wFD}, {(const float*)d_in[21], fvwb, wFD},
        };
        for (int i = 0; i < 7; ++i)
            cvt_fp8<<<dim3(2048), dim3(256), 0, stream>>>(cv[i].s, cv[i].d, (long)cv[i].n);
        P.kw = kwb; P.vw = vwb; P.rw = rwb; P.ow = owb; P.fkw = fkwb; P.fvw = fvwb; P.frw = frwb;
        spike_wave<true><<<dim3(NBLK), dim3(NTH), 0, stream>>>(P);
    } else {
        P.kw = d_in[14]; P.vw = d_in[15]; P.rw = d_in[16]; P.ow = d_in[17];
        P.fkw = d_in[20]; P.fvw = d_in[21]; P.frw = d_in[22];
        spike_wave<false><<<dim3(NBLK), dim3(NTH), 0, stream>>>(P);
    }
    int nwave = (VV + 7) / 8;
    int nblk  = (nwave + 3) / 4;
    head_simple<<<dim3(nblk), dim3(256), 0, stream>>>((const float*)d_in[25], XbT,
                                                      (float*)d_out);
}